// Round 7
// baseline (295.570 us; speedup 1.0000x reference)
//
#include <hip/hip_runtime.h>
#include <hip/hip_bf16.h>

typedef __hip_bfloat16 bf16;
typedef __attribute__((ext_vector_type(8))) short short8;
typedef __attribute__((ext_vector_type(4))) float f32x4;
typedef unsigned short u16;
typedef unsigned int u32;

static __device__ __forceinline__ u16 f2bs(float f) {
    bf16 h = __float2bfloat16(f);
    return *reinterpret_cast<u16*>(&h);
}
static __device__ __forceinline__ float bs2f(u16 u) {
    union { float f; u32 i; } x; x.i = ((u32)u) << 16; return x.f;
}
static __device__ __forceinline__ uint4 pack8(const u16* p) {
    uint4 v;
    v.x = (u32)p[0] | ((u32)p[1] << 16);
    v.y = (u32)p[2] | ((u32)p[3] << 16);
    v.z = (u32)p[4] | ((u32)p[5] << 16);
    v.w = (u32)p[6] | ((u32)p[7] << 16);
    return v;
}
// async global->LDS DMA, 16B per lane. Per-lane GLOBAL address, wave-uniform LDS base.
static __device__ __forceinline__ void gl16(const short* g, short* l) {
    __builtin_amdgcn_global_load_lds(
        (const __attribute__((address_space(1))) u32*)(g),
        (__attribute__((address_space(3))) u32*)(l), 16, 0, 0);
}

// =================== weight prep ===================
// classic layout [ocblk][ch][pr][mt][lane][j] (used by conv3_v3 for the idwt conv)
__device__ __forceinline__ void prep3_body(const float* __restrict__ w, short* __restrict__ wF,
                                           int C, int idx) {
    int j = idx & 7;
    int lane = (idx >> 3) & 63;
    int mt = (idx >> 9) & 3;
    int rest = idx >> 11;
    int pair = rest % 5;
    int bo = rest / 5;
    int nchunks = C / 16;
    int ch = bo % nchunks;
    int ocblk = bo / nchunks;
    int s = ((lane >> 4) * 8 + j);
    int tp = 2 * pair + (s >> 4);
    int ci = ch * 16 + (s & 15);
    int oc = ocblk * 64 + mt * 16 + (lane & 15);
    float v = (tp <= 8) ? w[((size_t)(oc * C + ci)) * 9 + tp] : 0.f;
    wF[idx] = (short)f2bs(v);
}
// phase-major layout [ch][pr][ocg][mt][lane][j] for conv3_v10 (4KB per (phase,ocg))
__device__ __forceinline__ void prep3_chpr(const float* __restrict__ w, short* __restrict__ wF,
                                           int idx) {
    int j = idx & 7;
    int lane = (idx >> 3) & 63;
    int mt = (idx >> 9) & 3;
    int rest = idx >> 11;
    int ocg = rest & 3;
    int r2 = rest >> 2;
    int pr = r2 % 5;
    int ch = r2 / 5;
    int s = ((lane >> 4) * 8 + j);
    int tp = 2 * pr + (s >> 4);
    int ci = ch * 16 + (s & 15);
    int oc = ocg * 64 + mt * 16 + (lane & 15);
    float v = (tp <= 8) ? w[((size_t)(oc * 256 + ci)) * 9 + tp] : 0.f;
    wF[idx] = (short)f2bs(v);
}
__device__ __forceinline__ void prep1_body(const float* __restrict__ w, short* __restrict__ wF,
                                           int Cin, int cioff, int nchunks, int idx) {
    int j = idx & 7;
    int lane = (idx >> 3) & 63;
    int mt = (idx >> 9) & 3;
    int bo = idx >> 11;
    int ch = bo % nchunks;
    int ocblk = bo / nchunks;
    int s = (lane >> 4) * 8 + j;
    int ci = cioff + ch * 32 + s;
    int oc = ocblk * 64 + mt * 16 + (lane & 15);
    wF[idx] = (short)f2bs(w[(size_t)oc * Cin + ci]);
}

__global__ __launch_bounds__(256) void prep_all(
        const float* __restrict__ wdwt, const float* __restrict__ widwt,
        const float* __restrict__ w2, const float* __restrict__ wproj,
        const float* __restrict__ w1,
        short* __restrict__ wF1, short* __restrict__ wF2c, short* __restrict__ wFk,
        short* __restrict__ wpF, short* __restrict__ wFq, float* __restrict__ scr) {
    int blk = blockIdx.x;
    int tid = threadIdx.x;
    if (blk < 2560) {
        prep3_chpr(wdwt, wF1, blk * 256 + tid);
    } else if (blk < 2720) {
        prep3_body(widwt, wF2c, 64, (blk - 2560) * 256 + tid);
    } else if (blk < 2976) {
        prep1_body(w2, wFk, 256, 0, 8, (blk - 2720) * 256 + tid);
    } else if (blk < 2992) {
        prep1_body(wproj, wpF, 128, 64, 2, (blk - 2976) * 256 + tid);
    } else if (blk < 3008) {
        prep1_body(w1, wFq, 64, 0, 2, (blk - 2992) * 256 + tid);
    } else {
        for (int i = tid; i < 4864; i += 256) scr[i] = 0.f;
    }
}

// =================== fused Haar DWT + Q conv ===================
__global__ __launch_bounds__(256) void dwtq_kernel(
        const float* __restrict__ x, const short* __restrict__ wFq,
        const float* __restrict__ b1, short* __restrict__ d0, short* __restrict__ outQ) {
    __shared__ short ls[256 * 72];
    int tid = threadIdx.x;
    int lane = tid & 63, wv = tid >> 6;
    int q = lane >> 4, pl = lane & 15;
    int xh = blockIdx.x;
    int y2 = blockIdx.y;
    int b = blockIdx.z;
    int x0 = xh * 128;

    #pragma unroll
    for (int k2 = 0; k2 < 16; ++k2) {
        int u = k2 * 256 + tid;
        int ch = u & 63;
        int xu = (u >> 6) & 31;
        int r = (u >> 11) & 1;
        float4 v = *(const float4*)(x + (((size_t)(b * 64 + ch) * 256 + (2 * y2 + r))) * 256 + x0 + xu * 4);
        ls[(r * 128 + xu * 4 + 0) * 72 + ch] = (short)f2bs(v.x);
        ls[(r * 128 + xu * 4 + 1) * 72 + ch] = (short)f2bs(v.y);
        ls[(r * 128 + xu * 4 + 2) * 72 + ch] = (short)f2bs(v.z);
        ls[(r * 128 + xu * 4 + 3) * 72 + ch] = (short)f2bs(v.w);
    }
    __syncthreads();

    f32x4 acc[4][4];
    #pragma unroll
    for (int mt = 0; mt < 4; ++mt)
        #pragma unroll
        for (int nt = 0; nt < 4; ++nt)
            acc[mt][nt] = (f32x4){0.f, 0.f, 0.f, 0.f};
    #pragma unroll
    for (int chk = 0; chk < 2; ++chk) {
        short8 af[4];
        #pragma unroll
        for (int mt = 0; mt < 4; ++mt)
            af[mt] = *(const short8*)(wFq + (chk * 4 + mt) * 512 + lane * 8);
        #pragma unroll
        for (int nt = 0; nt < 4; ++nt) {
            int p = wv * 64 + nt * 16 + pl;
            short8 bfr = *(const short8*)(ls + p * 72 + chk * 32 + q * 8);
            #pragma unroll
            for (int mt = 0; mt < 4; ++mt)
                acc[mt][nt] = __builtin_amdgcn_mfma_f32_16x16x32_bf16(af[mt], bfr, acc[mt][nt], 0, 0, 0);
        }
    }
    #pragma unroll
    for (int mt = 0; mt < 4; ++mt) {
        int ocb = mt * 16 + q * 4;
        float4 bi = *(const float4*)(b1 + ocb);
        float bia[4] = {bi.x, bi.y, bi.z, bi.w};
        #pragma unroll
        for (int nt = 0; nt < 4; ++nt) {
            int p = wv * 64 + nt * 16 + pl;
            int n = (2 * y2 + (p >> 7)) * 256 + x0 + (p & 127);
            #pragma unroll
            for (int r = 0; r < 4; ++r)
                outQ[((size_t)(b * 64 + ocb + r)) * 65536 + n] = (short)f2bs(acc[mt][nt][r] + bia[r]);
        }
    }

    int xl = tid >> 2;
    int cg = tid & 3;
    int c0 = cg * 16;
    u16 obuf[4][16];
    #pragma unroll
    for (int cl = 0; cl < 16; ++cl) {
        int c = c0 + cl;
        float a  = bs2f(ls[(2 * xl) * 72 + c]);
        float bb = bs2f(ls[(2 * xl + 1) * 72 + c]);
        float c2 = bs2f(ls[(128 + 2 * xl) * 72 + c]);
        float dd = bs2f(ls[(128 + 2 * xl + 1) * 72 + c]);
        obuf[0][cl] = f2bs((a - bb + c2 - dd) * 0.5f);  // lh
        obuf[1][cl] = f2bs((a + bb - c2 - dd) * 0.5f);  // hl
        obuf[2][cl] = f2bs((a - bb - c2 + dd) * 0.5f);  // hh
        obuf[3][cl] = f2bs((a + bb + c2 + dd) * 0.5f);  // ll
    }
    int xd = xh * 64 + xl;
    size_t P = ((size_t)(b * 128 + y2) * 128 + xd) * 256;
    #pragma unroll
    for (int g = 0; g < 4; ++g) {
        *(uint4*)&d0[P + g * 64 + c0]     = pack8(&obuf[g][0]);
        *(uint4*)&d0[P + g * 64 + c0 + 8] = pack8(&obuf[g][8]);
    }
}

// =================== Haar IDWT ===================
__global__ __launch_bounds__(256) void idwt_kernel(const short* __restrict__ d1, short* __restrict__ i0) {
    int tid = threadIdx.x;
    int lane = tid & 63;
    int p = blockIdx.x * 4 + (tid >> 6);
    int b = p >> 14, m = p & 16383;
    ushort4 v = *(const ushort4*)(d1 + ((size_t)(b * 16384 + m)) * 256 + 4 * lane);
    float yl = bs2f(v.x), lh = bs2f(v.y), hl = bs2f(v.z), hh = bs2f(v.w);
    float a_ = (yl + lh + hl + hh) * 0.5f;
    float b_ = (yl - lh + hl - hh) * 0.5f;
    float c_ = (yl + lh - hl - hh) * 0.5f;
    float d_ = (yl - lh - hl + hh) * 0.5f;
    int y = m >> 7, xx = m & 127;
    u16* o = (u16*)i0;
    size_t base = ((size_t)(b * 256 + 2 * y) * 256 + 2 * xx) * 64 + lane;
    o[base] = f2bs(a_);
    o[base + 64] = f2bs(b_);
    o[base + 256 * 64] = f2bs(c_);
    o[base + 256 * 64 + 64] = f2bs(d_);
}

// =================== 3x3 conv v10 (C=256, H=W=128): 4mt x 4nt wave tiles, 2 rows/block ===
// v9 was LDS-read-throughput bound: 4mt x 2nt = 6 ds_read_b128 per 8 MFMA -> 38.5us of
// LDS-port time vs 20.7us MFMA floor (sum = measured 60.7). FLOP-per-read scales as
// M*N/(M+N) of the per-wave tile, so v10 gives each wave a 64oc x 64px tile:
//   block = 4 waves x 64 oc (one ocg) x 2 output rows (256 px).
//   wave wv: row = wv>>1, col-half = wv&1; per phase reads 4 wfrag + 4 bfrag = 8
//   ds_read_b128 feeding 16 MFMA (0.5 reads/MFMA, 1.5x less port traffic than v9).
// Grid (64 row-pairs, 4 ocg, 2 b) = 512 blocks = 2 independent barrier groups/CU.
// XCD placement: 64%8==0 so all 4 ocg-blocks of a row-pair share an XCD; rp swizzle
// gives each XCD a contiguous 16-row band (L2-local halo + write-combined lines).
// Weights: 2-slot 4KB DMA ring staged 1 phase ahead; input 4 staged rows, dbuf'd.
__global__ __launch_bounds__(256, 2) void conv3_v10(
        const short* __restrict__ in, const short* __restrict__ wF,
        const float* __restrict__ bias, short* __restrict__ out) {
    constexpr int C = 256, W = 128, H = 128;
    constexpr int Wp = W + 2;              // 130 staged cols
    constexpr int UNITS = 4 * Wp * 2;      // 1040 16B-units per input chunk (4 rows)
    constexpr int UPT = 5;                 // ceil(1040/256)
    __shared__ short ibuf[2][4 * Wp * 16]; // 2 x 16.64 KB
    __shared__ short wslot[2][2048];       // 2 x 4 KB (one ocg's (ch,pr) slice)

    int tid = threadIdx.x;
    int lane = tid & 63, wv = tid >> 6;
    int q = lane >> 4, pl = lane & 15;
    int ocg = blockIdx.y;
    int bx = blockIdx.x;                   // row-pair index 0..63
    int rp = ((bx & 7) << 3) | (bx >> 3);  // bijective 8x8: XCD k owns row-pairs [8k,8k+8)
    int y0 = rp * 2;
    int b = blockIdx.z;
    int orow = wv >> 1;                    // which of the 2 output rows
    int colbase = (wv & 1) * 64;           // which 64-px half

    // per-lane global input source addresses (5 stage units/thread, last partial)
    const short* gp[UPT];
    int ibo[UPT];
    bool act[UPT];
    #pragma unroll
    for (int k2 = 0; k2 < UPT; ++k2) {
        int u = k2 * 256 + tid;
        act[k2] = (u < UNITS);
        int uu = act[k2] ? u : 0;
        int r = uu / (Wp * 2);
        int rem = uu - r * (Wp * 2);
        int px = rem >> 1, hf = rem & 1;
        int ry = y0 - 1 + r;
        if (ry < 0) ry = 1;
        if (ry >= H) ry = 2 * H - 2 - ry;
        int rx = px - 1;
        if (rx < 0) rx = 1;
        if (rx >= W) rx = W - 2;
        gp[k2] = in + ((b * H + ry) * W + rx) * C + hf * 8;
        ibo[k2] = (k2 * 256 + wv * 64) * 8;   // wave-uniform LDS base (lane*16B auto)
    }

    f32x4 acc[4][4];
    #pragma unroll
    for (int mt = 0; mt < 4; ++mt)
        #pragma unroll
        for (int nt = 0; nt < 4; ++nt)
            acc[mt][nt] = (f32x4){0.f, 0.f, 0.f, 0.f};

    // prologue: stage phase 0 weights (this ocg) + input chunk 0
    gl16(wF + ((size_t)0 * 4 + ocg) * 2048 + tid * 8, &wslot[0][wv * 64 * 8]);
    #pragma unroll
    for (int k2 = 0; k2 < UPT; ++k2)
        if (act[k2]) gl16(gp[k2], &ibuf[0][ibo[k2]]);
    __syncthreads();

    #pragma unroll 1
    for (int ch = 0; ch < 16; ++ch) {
        const short* ib = ibuf[ch & 1];
        #pragma unroll
        for (int pr = 0; pr < 5; ++pr) {
            int P = ch * 5 + pr;
            // stage next phase's 4KB weight slice into the other slot
            if (P < 79)
                gl16(wF + ((size_t)(P + 1) * 4 + ocg) * 2048 + tid * 8,
                     &wslot[(P + 1) & 1][wv * 64 * 8]);
            // at pr==1, stage next chunk's input
            if (pr == 1 && ch < 15) {
                short* id = ibuf[(ch + 1) & 1];
                #pragma unroll
                for (int k2 = 0; k2 < UPT; ++k2)
                    if (act[k2]) gl16(gp[k2] + (ch + 1) * 16, id + ibo[k2]);
            }
            // compute: 4 weight frags + 4 input frags from LDS, 16 MFMA
            const short* wb = wslot[P & 1];
            short8 wfrag[4];
            #pragma unroll
            for (int mt = 0; mt < 4; ++mt)
                wfrag[mt] = *(const short8*)(wb + mt * 512 + lane * 8);
            int t1 = 2 * pr + (q >> 1);
            if (t1 > 8) t1 = 8;
            int ti = (t1 >= 6) ? 2 : ((t1 >= 3) ? 1 : 0);
            int tj = t1 - ti * 3;
            #pragma unroll
            for (int nt = 0; nt < 4; ++nt) {
                int i = colbase + nt * 16 + pl + tj;
                short8 bfr = *(const short8*)(ib + ((ti + orow) * Wp + i) * 16 + (q & 1) * 8);
                #pragma unroll
                for (int mt = 0; mt < 4; ++mt)
                    acc[mt][nt] = __builtin_amdgcn_mfma_f32_16x16x32_bf16(wfrag[mt], bfr, acc[mt][nt], 0, 0, 0);
            }
            __syncthreads();
        }
    }

    int yout = y0 + orow;
    #pragma unroll
    for (int mt = 0; mt < 4; ++mt) {
        int ocb = ocg * 64 + mt * 16 + q * 4;
        float4 bi = *(const float4*)(bias + ocb);
        float bia[4] = {bi.x, bi.y, bi.z, bi.w};
        #pragma unroll
        for (int nt = 0; nt < 4; ++nt) {
            int xl = colbase + nt * 16 + pl;
            ushort4 pk;
            float v0 = acc[mt][nt][0] + bia[0]; pk.x = f2bs(v0 >= 0.f ? v0 : 0.01f * v0);
            float v1 = acc[mt][nt][1] + bia[1]; pk.y = f2bs(v1 >= 0.f ? v1 : 0.01f * v1);
            float v2 = acc[mt][nt][2] + bia[2]; pk.z = f2bs(v2 >= 0.f ? v2 : 0.01f * v2);
            float v3 = acc[mt][nt][3] + bia[3]; pk.w = f2bs(v3 >= 0.f ? v3 : 0.01f * v3);
            *(ushort4*)(out + (((size_t)(b * H + yout)) * W + xl) * C + ocb) = pk;
        }
    }
}

// =================== 3x3 conv v3 (kept for the 64-ch idwt conv) ===================
template <int C, int NPX, int WPG>
__global__ __launch_bounds__(256) void conv3_v3(
        const short* __restrict__ in, const short* __restrict__ wF,
        const float* __restrict__ bias, short* __restrict__ out,
        int H, int W) {
    constexpr int Wp = NPX + 2;
    constexpr int NCH = C / 16;
    constexpr int UNITS = 3 * Wp * 2;
    constexpr int UPT = (UNITS + 255) / 256;
    constexpr int BUFSZ = 3 * Wp * 16;
    extern __shared__ __align__(16) short inS[];

    int tid = threadIdx.x;
    int lane = tid & 63, wv = tid >> 6;
    int q = lane >> 4, pl = lane & 15;
    int ocg = wv / WPG;
    int pxoff = (wv % WPG) * 64;
    int x0 = blockIdx.x * NPX;
    int y = blockIdx.y;
    int b = blockIdx.z;

    int gbase[UPT];
    int ldsoff[UPT];
    #pragma unroll
    for (int k2 = 0; k2 < UPT; ++k2) {
        int u = k2 * 256 + tid;
        if (u < UNITS) {
            int r = u / (Wp * 2);
            int rem = u - r * (Wp * 2);
            int px = rem >> 1, hf = rem & 1;
            int ry = y - 1 + r;
            if (ry < 0) ry = 1;
            if (ry >= H) ry = H - 2;
            int rx = x0 - 1 + px;
            if (rx < 0) rx = 1;
            if (rx >= W) rx = W - 2;
            gbase[k2] = ((b * H + ry) * W + rx) * C + hf * 8;
            ldsoff[k2] = (r * Wp + px) * 16 + hf * 8;
        } else { gbase[k2] = 0; ldsoff[k2] = -1; }
    }

    f32x4 acc[4][4];
    #pragma unroll
    for (int mt = 0; mt < 4; ++mt)
        #pragma unroll
        for (int nt = 0; nt < 4; ++nt)
            acc[mt][nt] = (f32x4){0.f, 0.f, 0.f, 0.f};

    uint4 pf[UPT];
    #pragma unroll
    for (int k2 = 0; k2 < UPT; ++k2)
        if (ldsoff[k2] >= 0) pf[k2] = *(const uint4*)(in + gbase[k2]);
    #pragma unroll
    for (int k2 = 0; k2 < UPT; ++k2)
        if (ldsoff[k2] >= 0) *(uint4*)(inS + ldsoff[k2]) = pf[k2];
    __syncthreads();

    #pragma unroll 1
    for (int ch = 0; ch < NCH; ++ch) {
        const short* buf = inS + (ch & 1) * BUFSZ;
        short* nbuf = inS + ((ch + 1) & 1) * BUFSZ;
        bool more = (ch + 1 < NCH);
        const short* wbase = wF + ((size_t)(ocg * NCH + ch) * 5) * 2048;
        short8 wreg[5][4];
        #pragma unroll
        for (int pr = 0; pr < 5; ++pr)
            #pragma unroll
            for (int mt = 0; mt < 4; ++mt)
                wreg[pr][mt] = *(const short8*)(wbase + (pr * 4 + mt) * 512 + lane * 8);
        if (more) {
            #pragma unroll
            for (int k2 = 0; k2 < UPT; ++k2)
                if (ldsoff[k2] >= 0) pf[k2] = *(const uint4*)(in + gbase[k2] + (ch + 1) * 16);
        }
        #pragma unroll
        for (int pr = 0; pr < 5; ++pr) {
            int t1 = 2 * pr + (q >> 1);
            if (t1 > 8) t1 = 8;
            int ti = (t1 >= 6) ? 2 : ((t1 >= 3) ? 1 : 0);
            int tj = t1 - ti * 3;
            #pragma unroll
            for (int nt = 0; nt < 4; ++nt) {
                int i = pxoff + nt * 16 + pl + tj;
                short8 bfr = *(const short8*)(buf + (ti * Wp + i) * 16 + (q & 1) * 8);
                #pragma unroll
                for (int mt = 0; mt < 4; ++mt)
                    acc[mt][nt] = __builtin_amdgcn_mfma_f32_16x16x32_bf16(wreg[pr][mt], bfr, acc[mt][nt], 0, 0, 0);
            }
        }
        if (more) {
            #pragma unroll
            for (int k2 = 0; k2 < UPT; ++k2)
                if (ldsoff[k2] >= 0) *(uint4*)(nbuf + ldsoff[k2]) = pf[k2];
            __syncthreads();
        }
    }

    #pragma unroll
    for (int mt = 0; mt < 4; ++mt) {
        int ocb = ocg * 64 + mt * 16 + q * 4;
        float4 bi = *(const float4*)(bias + ocb);
        float bia[4] = {bi.x, bi.y, bi.z, bi.w};
        #pragma unroll
        for (int nt = 0; nt < 4; ++nt) {
            int xl = x0 + pxoff + nt * 16 + pl;
            ushort4 pk;
            float v0 = acc[mt][nt][0] + bia[0]; pk.x = f2bs(v0 >= 0.f ? v0 : 0.01f * v0);
            float v1 = acc[mt][nt][1] + bia[1]; pk.y = f2bs(v1 >= 0.f ? v1 : 0.01f * v1);
            float v2 = acc[mt][nt][2] + bia[2]; pk.z = f2bs(v2 >= 0.f ? v2 : 0.01f * v2);
            float v3 = acc[mt][nt][3] + bia[3]; pk.w = f2bs(v3 >= 0.f ? v3 : 0.01f * v3);
            *(ushort4*)(out + (((size_t)(b * H + y)) * W + xl) * C + ocb) = pk;
        }
    }
}

// =================== K conv 1x1 MFMA ===================
__global__ __launch_bounds__(256) void kconv_mfma(
        const short* __restrict__ in, const short* __restrict__ wF,
        const float* __restrict__ bias, short* __restrict__ outK) {
    __shared__ short inS[8192];
    int tid = threadIdx.x;
    int lane = tid & 63, wv = tid >> 6;
    int q = lane >> 4, pl = lane & 15;
    int ocblk = blockIdx.x;
    int m0 = blockIdx.y * 256;
    int b = blockIdx.z;
    int px0w = wv * 64;
    f32x4 acc[4][4];
    #pragma unroll
    for (int mt = 0; mt < 4; ++mt)
        #pragma unroll
        for (int nt = 0; nt < 4; ++nt)
            acc[mt][nt] = (f32x4){0.f, 0.f, 0.f, 0.f};

    for (int ch = 0; ch < 8; ++ch) {
        if (ch) __syncthreads();
        const short* src = in + ((size_t)(b * 16384 + m0)) * 256 + ch * 32;
        for (int t = tid; t < 1024; t += 256) {
            int pix = t >> 2, hf = t & 3;
            *(uint4*)(inS + pix * 32 + hf * 8) = *(const uint4*)(src + (size_t)pix * 256 + hf * 8);
        }
        short8 af[4];
        #pragma unroll
        for (int mt = 0; mt < 4; ++mt)
            af[mt] = *(const short8*)(wF + ((size_t)(ocblk * 8 + ch)) * 2048 + mt * 512 + lane * 8);
        __syncthreads();
        #pragma unroll
        for (int nt = 0; nt < 4; ++nt) {
            short8 bfr = *(const short8*)(inS + (px0w + nt * 16 + pl) * 32 + q * 8);
            #pragma unroll
            for (int mt = 0; mt < 4; ++mt)
                acc[mt][nt] = __builtin_amdgcn_mfma_f32_16x16x32_bf16(af[mt], bfr, acc[mt][nt], 0, 0, 0);
        }
    }
    #pragma unroll
    for (int mt = 0; mt < 4; ++mt) {
        int ocb = ocblk * 64 + mt * 16 + q * 4;
        float4 bi = *(const float4*)(bias + ocb);
        float bia[4] = {bi.x, bi.y, bi.z, bi.w};
        #pragma unroll
        for (int nt = 0; nt < 4; ++nt) {
            int n = m0 + px0w + nt * 16 + pl;
            #pragma unroll
            for (int r = 0; r < 4; ++r) {
                int co = ocb + r;
                outK[((size_t)(b * 64 + (co >> 2))) * 65536 + (co & 3) * 16384 + n] =
                    (short)f2bs(acc[mt][nt][r] + bia[r]);
            }
        }
    }
}

// =================== Gram via MFMA: per-head 16x16 Q.K^T + row norms ===================
__global__ __launch_bounds__(256) void gram_mfma(
        const short* __restrict__ Q, const short* __restrict__ K,
        float* __restrict__ qss, float* __restrict__ kss, float* __restrict__ gram) {
    int tid = threadIdx.x;
    int lane = tid & 63, h = tid >> 6;
    int q = lane >> 4, m = lane & 15;
    int b = blockIdx.y;
    int n0 = blockIdx.x * 512;
    const short* qrow = Q + ((size_t)(b * 64 + h * 16 + m)) * 65536 + n0 + q * 8;
    const short* krow = K + ((size_t)(b * 64 + h * 16 + m)) * 65536 + n0 + q * 8;
    f32x4 acc = (f32x4){0.f, 0.f, 0.f, 0.f};
    float sq = 0.f, sk = 0.f;
    #pragma unroll 4
    for (int it = 0; it < 16; ++it) {
        short8 aq = *(const short8*)(qrow + it * 32);
        short8 ak = *(const short8*)(krow + it * 32);
        acc = __builtin_amdgcn_mfma_f32_16x16x32_bf16(aq, ak, acc, 0, 0, 0);
        #pragma unroll
        for (int j = 0; j < 8; ++j) {
            float fq = bs2f((u16)aq[j]);
            float fk = bs2f((u16)ak[j]);
            sq += fq * fq;
            sk += fk * fk;
        }
    }
    sq += __shfl_xor(sq, 16); sq += __shfl_xor(sq, 32);
    sk += __shfl_xor(sk, 16); sk += __shfl_xor(sk, 32);
    if (q == 0) {
        atomicAdd(&qss[b * 64 + h * 16 + m], sq);
        atomicAdd(&kss[b * 64 + h * 16 + m], sk);
    }
    #pragma unroll
    for (int r = 0; r < 4; ++r) {
        int c = q * 4 + r;   // row of D
        atomicAdd(&gram[b * 1024 + h * 256 + c * 16 + m], acc[r]);
    }
}

// =================== softmax(cos-sim * temp) ===================
__global__ void attn_kernel(const float* __restrict__ gram, const float* __restrict__ qss,
                            const float* __restrict__ kss, const float* __restrict__ temp,
                            float* __restrict__ attn) {
    int bh = blockIdx.x;
    int b = bh >> 2, h = bh & 3;
    int tid = threadIdx.x;
    __shared__ float L[16][17];
    __shared__ float rowmax[16], rowsum[16];
    int c = tid >> 4, d = tid & 15;
    float qn = fmaxf(sqrtf(qss[b * 64 + h * 16 + c]), 1e-12f);
    float kn = fmaxf(sqrtf(kss[b * 64 + h * 16 + d]), 1e-12f);
    float lg = gram[b * 1024 + h * 256 + c * 16 + d] / (qn * kn) * temp[h];
    L[c][d] = lg;
    __syncthreads();
    if (tid < 16) {
        float m = -1e30f;
        for (int j = 0; j < 16; ++j) m = fmaxf(m, L[tid][j]);
        rowmax[tid] = m;
    }
    __syncthreads();
    float e = expf(lg - rowmax[c]);
    L[c][d] = e;
    __syncthreads();
    if (tid < 16) {
        float s = 0.f;
        for (int j = 0; j < 16; ++j) s += L[tid][j];
        rowsum[tid] = s;
    }
    __syncthreads();
    attn[b * 1024 + h * 256 + c * 16 + d] = e / rowsum[c];
}

// =================== fold v2 ===================
__global__ __launch_bounds__(256) void fold_v2(
        const float* __restrict__ attn, const float* __restrict__ w3,
        const float* __restrict__ b3, const float* __restrict__ wproj,
        short* __restrict__ WfoldF, float* __restrict__ bfold) {
    __shared__ float attn_s[1024];
    __shared__ float wp_s[64][65];
    __shared__ float Aeff_s[64][17];
    __shared__ float beff[64];
    int bt = blockIdx.y;
    int b = bt >> 2, t = bt & 3;
    int ci0 = blockIdx.x * 16;
    int tid = threadIdx.x;
    for (int i = 0; i < 4; ++i) attn_s[tid + i * 256] = attn[b * 1024 + tid + i * 256];
    #pragma unroll
    for (int i = 0; i < 16; ++i) {
        int idx = tid + i * 256;
        int co = idx >> 6, C = idx & 63;
        wp_s[co][C] = wproj[co * 128 + C];
    }
    __syncthreads();
    #pragma unroll
    for (int pass = 0; pass < 4; ++pass) {
        int el = pass * 256 + tid;
        int C = el >> 4, ci_l = el & 15;
        int h = C >> 4, c = C & 15;
        float s = 0.f;
        #pragma unroll
        for (int d = 0; d < 16; ++d)
            s += attn_s[h * 256 + c * 16 + d] * w3[(size_t)(4 * (h * 16 + d) + t) * 256 + ci0 + ci_l];
        Aeff_s[C][ci_l] = s;
    }
    if (blockIdx.x == 0 && tid < 64) {
        int h = tid >> 4, c = tid & 15;
        float s = 0.f;
        #pragma unroll
        for (int d = 0; d < 16; ++d)
            s += attn_s[h * 256 + c * 16 + d] * b3[4 * (h * 16 + d) + t];
        beff[tid] = s;
    }
    __syncthreads();
    #pragma unroll
    for (int pass = 0; pass < 4; ++pass) {
        int el = pass * 256 + tid;
        int ci_l = el >> 6, co = el & 63;
        float s = 0.f;
        #pragma unroll
        for (int C = 0; C < 64; ++C) s += wp_s[co][C] * Aeff_s[C][ci_l];
        int ci = ci0 + ci_l;
        int chk = ci >> 5;
        int s5 = ci & 31;
        int j = s5 & 7;
        int lane2 = (((s5 >> 3) << 4)) | (co & 15);
        int mt = co >> 4;
        WfoldF[(((size_t)(bt * 8 + chk) * 4 + mt)) * 512 + lane2 * 8 + j] = (short)f2bs(s);
    }
    if (blockIdx.x == 0 && tid < 64) {
        float s = 0.f;
        #pragma unroll
        for (int C = 0; C < 64; ++C) s += wp_s[tid][C] * beff[C];
        bfold[bt * 64 + tid] = s;
    }
}

// =================== final: out = Wfold[b,t]·D1 + bfold + Wp2·I2, fp32 out ===================
__global__ __launch_bounds__(256) void final_mfma(
        const short* __restrict__ D1, const short* __restrict__ I2,
        const short* __restrict__ WfoldF, const short* __restrict__ wpF,
        const float* __restrict__ bfold, float* __restrict__ out) {
    __shared__ short inS[8192];
    int tid = threadIdx.x;
    int lane = tid & 63, wv = tid >> 6;
    int q = lane >> 4, pl = lane & 15;
    int n0 = blockIdx.x * 256;
    int b = blockIdx.y;
    int t = n0 >> 14, m0 = n0 & 16383, bt = b * 4 + t;
    int px0w = wv * 64;
    f32x4 acc[4][4];
    #pragma unroll
    for (int mt = 0; mt < 4; ++mt) {
        float4 bf4 = *(const float4*)(bfold + bt * 64 + mt * 16 + q * 4);
        #pragma unroll
        for (int nt = 0; nt < 4; ++nt)
            acc[mt][nt] = (f32x4){bf4.x, bf4.y, bf4.z, bf4.w};
    }
    for (int ch = 0; ch < 8; ++ch) {
        if (ch) __syncthreads();
        const short* src = D1 + ((size_t)(b * 16384 + m0)) * 256 + ch * 32;
        for (int tt = tid; tt < 1024; tt += 256) {
            int pix = tt >> 2, hf = tt & 3;
            *(uint4*)(inS + pix * 32 + hf * 8) = *(const uint4*)(src + (size_t)pix * 256 + hf * 8);
        }
        short8 af[4];
        #pragma unroll
        for (int mt = 0; mt < 4; ++mt)
            af[mt] = *(const short8*)(WfoldF + ((size_t)(bt * 8 + ch)) * 2048 + mt * 512 + lane * 8);
        __syncthreads();
        #pragma unroll
        for (int nt = 0; nt < 4; ++nt) {
            short8 bfr = *(const short8*)(inS + (px0w + nt * 16 + pl) * 32 + q * 8);
            #pragma unroll
            for (int mt = 0; mt < 4; ++mt)
                acc[mt][nt] = __builtin_amdgcn_mfma_f32_16x16x32_bf16(af[mt], bfr, acc[mt][nt], 0, 0, 0);
        }
    }
    for (int ch = 0; ch < 2; ++ch) {
        __syncthreads();
        const short* src = I2 + ((size_t)(b * 65536 + n0)) * 64 + ch * 32;
        for (int tt = tid; tt < 1024; tt += 256) {
            int pix = tt >> 2, hf = tt & 3;
            *(uint4*)(inS + pix * 32 + hf * 8) = *(const uint4*)(src + (size_t)pix * 64 + hf * 8);
        }
        short8 af[4];
        #pragma unroll
        for (int mt = 0; mt < 4; ++mt)
            af[mt] = *(const short8*)(wpF + (size_t)ch * 2048 + mt * 512 + lane * 8);
        __syncthreads();
        #pragma unroll
        for (int nt = 0; nt < 4; ++nt) {
            short8 bfr = *(const short8*)(inS + (px0w + nt * 16 + pl) * 32 + q * 8);
            #pragma unroll
            for (int mt = 0; mt < 4; ++mt)
                acc[mt][nt] = __builtin_amdgcn_mfma_f32_16x16x32_bf16(af[mt], bfr, acc[mt][nt], 0, 0, 0);
        }
    }
    #pragma unroll
    for (int mt = 0; mt < 4; ++mt) {
        #pragma unroll
        for (int nt = 0; nt < 4; ++nt) {
            int n = n0 + px0w + nt * 16 + pl;
            #pragma unroll
            for (int r = 0; r < 4; ++r) {
                int co = mt * 16 + q * 4 + r;
                out[((size_t)(b * 64 + co)) * 65536 + n] = acc[mt][nt][r];
            }
        }
    }
}

extern "C" void kernel_launch(void* const* d_in, const int* in_sizes, int n_in,
                              void* d_out, int out_size, void* d_ws, size_t ws_size,
                              hipStream_t stream) {
    const float* x     = (const float*)d_in[0];
    const float* temp  = (const float*)d_in[1];
    const float* w1    = (const float*)d_in[2];
    const float* b1    = (const float*)d_in[3];
    const float* w2    = (const float*)d_in[4];
    const float* b2    = (const float*)d_in[5];
    const float* w3    = (const float*)d_in[6];
    const float* b3    = (const float*)d_in[7];
    const float* wdwt  = (const float*)d_in[8];
    const float* bdwt  = (const float*)d_in[9];
    const float* widwt = (const float*)d_in[10];
    const float* bidwt = (const float*)d_in[11];
    const float* wproj = (const float*)d_in[12];
    float* out = (float*)d_out;

    char* W8 = (char*)d_ws;
    const size_t SLOT = 16777216;
    short* slotA = (short*)(W8);              // D0 -> I0
    short* slotB = (short*)(W8 + SLOT);       // D1
    short* slotC = (short*)(W8 + 2 * SLOT);   // Qb -> I2
    short* slotD = (short*)(W8 + 3 * SLOT);   // Kb
    char* P = W8 + 4 * SLOT;
    short* wF1    = (short*)P; P += 2 * 655360;
    short* wF2c   = (short*)P; P += 2 * 40960;
    short* wFk    = (short*)P; P += 2 * 65536;
    short* wpF    = (short*)P; P += 2 * 4096;
    short* wFq    = (short*)P; P += 2 * 4096;
    short* WfoldF = (short*)P; P += 2 * 131072;
    float* scr    = (float*)P;
    float* qss   = scr;
    float* kss   = scr + 128;
    float* gram  = scr + 256;
    float* attn  = scr + 2304;
    float* bfold = scr + 4352;

    prep_all<<<3009, 256, 0, stream>>>(wdwt, widwt, w2, wproj, w1,
                                       wF1, wF2c, wFk, wpF, wFq, scr);

    // fused DWT + Q conv (x read once): D0 -> slotA, Qb -> slotC
    dwtq_kernel<<<dim3(2, 128, 2), 256, 0, stream>>>(x, wFq, b1, slotA, slotC);

    // DWT-branch 3x3 conv — v10: 4mt x 4nt wave tiles (0.5 LDS reads/MFMA), 2 rows/block
    conv3_v10<<<dim3(64, 4, 2), 256, 0, stream>>>(slotA, wF1, bdwt, slotB);

    // K conv + gram (frees slotC after gram)
    kconv_mfma<<<dim3(4, 64, 2), 256, 0, stream>>>(slotB, wFk, b2, slotD);
    gram_mfma<<<dim3(128, 2), 256, 0, stream>>>(slotC, slotD, qss, kss, gram);

    // IDWT branch (slotA reused for I0, slotC reused for I2)
    idwt_kernel<<<8192, 256, 0, stream>>>(slotB, slotA);
    conv3_v3<64, 256, 4><<<dim3(1, 256, 2), 256, 49536, stream>>>(slotA, wF2c, bidwt, slotC, 256, 256);

    // softmax -> fold
    attn_kernel<<<8, 256, 0, stream>>>(gram, qss, kss, temp, attn);
    fold_v2<<<dim3(16, 8), 256, 0, stream>>>(attn, w3, b3, wproj, WfoldF, bfold);

    // fused (attn·V + proj) + idwt-branch proj
    final_mfma<<<dim3(256, 2), 256, 0, stream>>>(slotB, slotC, WfoldF, wpF, bfold, out);
}

// Round 8
// 290.675 us; speedup vs baseline: 1.0168x; 1.0168x over previous
//
#include <hip/hip_runtime.h>
#include <hip/hip_bf16.h>

typedef __hip_bfloat16 bf16;
typedef __attribute__((ext_vector_type(8))) short short8;
typedef __attribute__((ext_vector_type(4))) float f32x4;
typedef unsigned short u16;
typedef unsigned int u32;

static __device__ __forceinline__ u16 f2bs(float f) {
    bf16 h = __float2bfloat16(f);
    return *reinterpret_cast<u16*>(&h);
}
static __device__ __forceinline__ float bs2f(u16 u) {
    union { float f; u32 i; } x; x.i = ((u32)u) << 16; return x.f;
}
static __device__ __forceinline__ uint4 pack8(const u16* p) {
    uint4 v;
    v.x = (u32)p[0] | ((u32)p[1] << 16);
    v.y = (u32)p[2] | ((u32)p[3] << 16);
    v.z = (u32)p[4] | ((u32)p[5] << 16);
    v.w = (u32)p[6] | ((u32)p[7] << 16);
    return v;
}
// async global->LDS DMA, 16B per lane. Per-lane GLOBAL address, wave-uniform LDS base.
static __device__ __forceinline__ void gl16(const short* g, short* l) {
    __builtin_amdgcn_global_load_lds(
        (const __attribute__((address_space(1))) u32*)(g),
        (__attribute__((address_space(3))) u32*)(l), 16, 0, 0);
}

// =================== weight prep ===================
// classic layout [ocblk][ch][pr][mt][lane][j] (used by conv3_v3 for the idwt conv)
__device__ __forceinline__ void prep3_body(const float* __restrict__ w, short* __restrict__ wF,
                                           int C, int idx) {
    int j = idx & 7;
    int lane = (idx >> 3) & 63;
    int mt = (idx >> 9) & 3;
    int rest = idx >> 11;
    int pair = rest % 5;
    int bo = rest / 5;
    int nchunks = C / 16;
    int ch = bo % nchunks;
    int ocblk = bo / nchunks;
    int s = ((lane >> 4) * 8 + j);
    int tp = 2 * pair + (s >> 4);
    int ci = ch * 16 + (s & 15);
    int oc = ocblk * 64 + mt * 16 + (lane & 15);
    float v = (tp <= 8) ? w[((size_t)(oc * C + ci)) * 9 + tp] : 0.f;
    wF[idx] = (short)f2bs(v);
}
// phase-major layout [ch][pr][ocg][mt][lane][j] for conv3_v11 (4KB per (phase,ocg))
__device__ __forceinline__ void prep3_chpr(const float* __restrict__ w, short* __restrict__ wF,
                                           int idx) {
    int j = idx & 7;
    int lane = (idx >> 3) & 63;
    int mt = (idx >> 9) & 3;
    int rest = idx >> 11;
    int ocg = rest & 3;
    int r2 = rest >> 2;
    int pr = r2 % 5;
    int ch = r2 / 5;
    int s = ((lane >> 4) * 8 + j);
    int tp = 2 * pr + (s >> 4);
    int ci = ch * 16 + (s & 15);
    int oc = ocg * 64 + mt * 16 + (lane & 15);
    float v = (tp <= 8) ? w[((size_t)(oc * 256 + ci)) * 9 + tp] : 0.f;
    wF[idx] = (short)f2bs(v);
}
__device__ __forceinline__ void prep1_body(const float* __restrict__ w, short* __restrict__ wF,
                                           int Cin, int cioff, int nchunks, int idx) {
    int j = idx & 7;
    int lane = (idx >> 3) & 63;
    int mt = (idx >> 9) & 3;
    int bo = idx >> 11;
    int ch = bo % nchunks;
    int ocblk = bo / nchunks;
    int s = (lane >> 4) * 8 + j;
    int ci = cioff + ch * 32 + s;
    int oc = ocblk * 64 + mt * 16 + (lane & 15);
    wF[idx] = (short)f2bs(w[(size_t)oc * Cin + ci]);
}

__global__ __launch_bounds__(256) void prep_all(
        const float* __restrict__ wdwt, const float* __restrict__ widwt,
        const float* __restrict__ w2, const float* __restrict__ wproj,
        const float* __restrict__ w1,
        short* __restrict__ wF1, short* __restrict__ wF2c, short* __restrict__ wFk,
        short* __restrict__ wpF, short* __restrict__ wFq, float* __restrict__ scr) {
    int blk = blockIdx.x;
    int tid = threadIdx.x;
    if (blk < 2560) {
        prep3_chpr(wdwt, wF1, blk * 256 + tid);
    } else if (blk < 2720) {
        prep3_body(widwt, wF2c, 64, (blk - 2560) * 256 + tid);
    } else if (blk < 2976) {
        prep1_body(w2, wFk, 256, 0, 8, (blk - 2720) * 256 + tid);
    } else if (blk < 2992) {
        prep1_body(wproj, wpF, 128, 64, 2, (blk - 2976) * 256 + tid);
    } else if (blk < 3008) {
        prep1_body(w1, wFq, 64, 0, 2, (blk - 2992) * 256 + tid);
    } else {
        for (int i = tid; i < 4864; i += 256) scr[i] = 0.f;
    }
}

// =================== fused Haar DWT + Q conv ===================
__global__ __launch_bounds__(256) void dwtq_kernel(
        const float* __restrict__ x, const short* __restrict__ wFq,
        const float* __restrict__ b1, short* __restrict__ d0, short* __restrict__ outQ) {
    __shared__ short ls[256 * 72];
    int tid = threadIdx.x;
    int lane = tid & 63, wv = tid >> 6;
    int q = lane >> 4, pl = lane & 15;
    int xh = blockIdx.x;
    int y2 = blockIdx.y;
    int b = blockIdx.z;
    int x0 = xh * 128;

    #pragma unroll
    for (int k2 = 0; k2 < 16; ++k2) {
        int u = k2 * 256 + tid;
        int ch = u & 63;
        int xu = (u >> 6) & 31;
        int r = (u >> 11) & 1;
        float4 v = *(const float4*)(x + (((size_t)(b * 64 + ch) * 256 + (2 * y2 + r))) * 256 + x0 + xu * 4);
        ls[(r * 128 + xu * 4 + 0) * 72 + ch] = (short)f2bs(v.x);
        ls[(r * 128 + xu * 4 + 1) * 72 + ch] = (short)f2bs(v.y);
        ls[(r * 128 + xu * 4 + 2) * 72 + ch] = (short)f2bs(v.z);
        ls[(r * 128 + xu * 4 + 3) * 72 + ch] = (short)f2bs(v.w);
    }
    __syncthreads();

    f32x4 acc[4][4];
    #pragma unroll
    for (int mt = 0; mt < 4; ++mt)
        #pragma unroll
        for (int nt = 0; nt < 4; ++nt)
            acc[mt][nt] = (f32x4){0.f, 0.f, 0.f, 0.f};
    #pragma unroll
    for (int chk = 0; chk < 2; ++chk) {
        short8 af[4];
        #pragma unroll
        for (int mt = 0; mt < 4; ++mt)
            af[mt] = *(const short8*)(wFq + (chk * 4 + mt) * 512 + lane * 8);
        #pragma unroll
        for (int nt = 0; nt < 4; ++nt) {
            int p = wv * 64 + nt * 16 + pl;
            short8 bfr = *(const short8*)(ls + p * 72 + chk * 32 + q * 8);
            #pragma unroll
            for (int mt = 0; mt < 4; ++mt)
                acc[mt][nt] = __builtin_amdgcn_mfma_f32_16x16x32_bf16(af[mt], bfr, acc[mt][nt], 0, 0, 0);
        }
    }
    #pragma unroll
    for (int mt = 0; mt < 4; ++mt) {
        int ocb = mt * 16 + q * 4;
        float4 bi = *(const float4*)(b1 + ocb);
        float bia[4] = {bi.x, bi.y, bi.z, bi.w};
        #pragma unroll
        for (int nt = 0; nt < 4; ++nt) {
            int p = wv * 64 + nt * 16 + pl;
            int n = (2 * y2 + (p >> 7)) * 256 + x0 + (p & 127);
            #pragma unroll
            for (int r = 0; r < 4; ++r)
                outQ[((size_t)(b * 64 + ocb + r)) * 65536 + n] = (short)f2bs(acc[mt][nt][r] + bia[r]);
        }
    }

    int xl = tid >> 2;
    int cg = tid & 3;
    int c0 = cg * 16;
    u16 obuf[4][16];
    #pragma unroll
    for (int cl = 0; cl < 16; ++cl) {
        int c = c0 + cl;
        float a  = bs2f(ls[(2 * xl) * 72 + c]);
        float bb = bs2f(ls[(2 * xl + 1) * 72 + c]);
        float c2 = bs2f(ls[(128 + 2 * xl) * 72 + c]);
        float dd = bs2f(ls[(128 + 2 * xl + 1) * 72 + c]);
        obuf[0][cl] = f2bs((a - bb + c2 - dd) * 0.5f);  // lh
        obuf[1][cl] = f2bs((a + bb - c2 - dd) * 0.5f);  // hl
        obuf[2][cl] = f2bs((a - bb - c2 + dd) * 0.5f);  // hh
        obuf[3][cl] = f2bs((a + bb + c2 + dd) * 0.5f);  // ll
    }
    int xd = xh * 64 + xl;
    size_t P = ((size_t)(b * 128 + y2) * 128 + xd) * 256;
    #pragma unroll
    for (int g = 0; g < 4; ++g) {
        *(uint4*)&d0[P + g * 64 + c0]     = pack8(&obuf[g][0]);
        *(uint4*)&d0[P + g * 64 + c0 + 8] = pack8(&obuf[g][8]);
    }
}

// =================== Haar IDWT ===================
__global__ __launch_bounds__(256) void idwt_kernel(const short* __restrict__ d1, short* __restrict__ i0) {
    int tid = threadIdx.x;
    int lane = tid & 63;
    int p = blockIdx.x * 4 + (tid >> 6);
    int b = p >> 14, m = p & 16383;
    ushort4 v = *(const ushort4*)(d1 + ((size_t)(b * 16384 + m)) * 256 + 4 * lane);
    float yl = bs2f(v.x), lh = bs2f(v.y), hl = bs2f(v.z), hh = bs2f(v.w);
    float a_ = (yl + lh + hl + hh) * 0.5f;
    float b_ = (yl - lh + hl - hh) * 0.5f;
    float c_ = (yl + lh - hl - hh) * 0.5f;
    float d_ = (yl - lh - hl + hh) * 0.5f;
    int y = m >> 7, xx = m & 127;
    u16* o = (u16*)i0;
    size_t base = ((size_t)(b * 256 + 2 * y) * 256 + 2 * xx) * 64 + lane;
    o[base] = f2bs(a_);
    o[base + 64] = f2bs(b_);
    o[base + 256 * 64] = f2bs(c_);
    o[base + 256 * 64 + 64] = f2bs(d_);
}

// =================== 3x3 conv v11 (C=256, H=W=128): reg-dbuf weights, no weight LDS ===
// v9/v10 both plateaued at 60.5us: every phase has a global_load_lds outstanding, so
// every __syncthreads compiles to s_waitcnt vmcnt(0) + s_barrier -> each of the 80
// phases serially pays the full DMA round-trip. Fix: weights never touch LDS/DMA.
// Per phase a wave needs only 4 frags (16 VGPR) and all 4 waves read the same 4KB
// (L1-broadcast), so a per-wave REGISTER ping-pong (wA/wB, loaded one phase ahead)
// pipelines across barriers -- plain register loads don't require a vmcnt drain at
// s_barrier. Only the 16 chunk-boundary input gl16 phases still drain.
// Geometry = v10: block = 4 waves x 64oc (one ocg) x 2 rows (256 px); wave owns a
// 64x64 tile (4mt x 4nt, 16 MFMA from 4 ds_read_b128). Grid (64 rp, 4 ocg, 2 b).
// XCD placement: 64%8==0 keeps a row-pair's 4 ocg-blocks on one XCD; rp-swizzle
// gives each XCD a contiguous 16-row band.
#define PHASE_V11(P, WC, WN)                                                      \
    {                                                                             \
        const int P_ = (P);                                                       \
        const int ch_ = P_ / 5;                                                   \
        const int pr_ = P_ - ch_ * 5;                                             \
        if (P_ + 1 < 80) {                                                        \
            const short* wn = wF + ((size_t)((P_ + 1) * 4 + ocg)) * 2048;         \
            _Pragma("unroll")                                                     \
            for (int mt = 0; mt < 4; ++mt)                                        \
                WN[mt] = *(const short8*)(wn + mt * 512 + lane * 8);              \
        }                                                                         \
        if (pr_ == 0 && ch_ < 15) {                                               \
            short* id = ibuf[(ch_ + 1) & 1];                                      \
            _Pragma("unroll")                                                     \
            for (int k2 = 0; k2 < UPT; ++k2)                                      \
                if (act[k2]) gl16(gp[k2] + (ch_ + 1) * 16, id + ibo[k2]);         \
        }                                                                         \
        const short* ib = ibuf[ch_ & 1];                                          \
        int t1 = 2 * pr_ + (q >> 1);                                              \
        if (t1 > 8) t1 = 8;                                                       \
        int ti = (t1 >= 6) ? 2 : ((t1 >= 3) ? 1 : 0);                             \
        int tj = t1 - ti * 3;                                                     \
        _Pragma("unroll")                                                         \
        for (int nt = 0; nt < 4; ++nt) {                                          \
            int i = colbase + nt * 16 + pl + tj;                                  \
            short8 bfr = *(const short8*)(ib + ((ti + orow) * Wp + i) * 16 + (q & 1) * 8); \
            _Pragma("unroll")                                                     \
            for (int mt = 0; mt < 4; ++mt)                                        \
                acc[mt][nt] = __builtin_amdgcn_mfma_f32_16x16x32_bf16(WC[mt], bfr, acc[mt][nt], 0, 0, 0); \
        }                                                                         \
        __syncthreads();                                                          \
    }

__global__ __launch_bounds__(256) void conv3_v11(
        const short* __restrict__ in, const short* __restrict__ wF,
        const float* __restrict__ bias, short* __restrict__ out) {
    constexpr int C = 256, W = 128, H = 128;
    constexpr int Wp = W + 2;              // 130 staged cols
    constexpr int UNITS = 4 * Wp * 2;      // 1040 16B-units per input chunk (4 rows)
    constexpr int UPT = 5;                 // ceil(1040/256)
    __shared__ short ibuf[2][4 * Wp * 16]; // 2 x 16.64 KB (input only; weights in regs)

    int tid = threadIdx.x;
    int lane = tid & 63, wv = tid >> 6;
    int q = lane >> 4, pl = lane & 15;
    int ocg = blockIdx.y;
    int bx = blockIdx.x;                   // row-pair index 0..63
    int rp = ((bx & 7) << 3) | (bx >> 3);  // bijective 8x8: XCD k owns row-pairs [8k,8k+8)
    int y0 = rp * 2;
    int b = blockIdx.z;
    int orow = wv >> 1;                    // which of the 2 output rows
    int colbase = (wv & 1) * 64;           // which 64-px half

    // per-lane global input source addresses (5 stage units/thread, last partial)
    const short* gp[UPT];
    int ibo[UPT];
    bool act[UPT];
    #pragma unroll
    for (int k2 = 0; k2 < UPT; ++k2) {
        int u = k2 * 256 + tid;
        act[k2] = (u < UNITS);
        int uu = act[k2] ? u : 0;
        int r = uu / (Wp * 2);
        int rem = uu - r * (Wp * 2);
        int px = rem >> 1, hf = rem & 1;
        int ry = y0 - 1 + r;
        if (ry < 0) ry = 1;
        if (ry >= H) ry = 2 * H - 2 - ry;
        int rx = px - 1;
        if (rx < 0) rx = 1;
        if (rx >= W) rx = W - 2;
        gp[k2] = in + ((b * H + ry) * W + rx) * C + hf * 8;
        ibo[k2] = (k2 * 256 + wv * 64) * 8;   // wave-uniform LDS base (lane*16B auto)
    }

    f32x4 acc[4][4];
    #pragma unroll
    for (int mt = 0; mt < 4; ++mt)
        #pragma unroll
        for (int nt = 0; nt < 4; ++nt)
            acc[mt][nt] = (f32x4){0.f, 0.f, 0.f, 0.f};

    // prologue: phase-0 weights -> wA (registers); input chunk 0 -> ibuf[0] (DMA)
    short8 wA[4], wB[4];
    {
        const short* w0 = wF + ((size_t)(0 * 4 + ocg)) * 2048;
        #pragma unroll
        for (int mt = 0; mt < 4; ++mt)
            wA[mt] = *(const short8*)(w0 + mt * 512 + lane * 8);
    }
    #pragma unroll
    for (int k2 = 0; k2 < UPT; ++k2)
        if (act[k2]) gl16(gp[k2], &ibuf[0][ibo[k2]]);
    __syncthreads();

    #pragma unroll 1
    for (int P2 = 0; P2 < 80; P2 += 2) {
        PHASE_V11(P2, wA, wB)
        PHASE_V11(P2 + 1, wB, wA)
    }

    int yout = y0 + orow;
    #pragma unroll
    for (int mt = 0; mt < 4; ++mt) {
        int ocb = ocg * 64 + mt * 16 + q * 4;
        float4 bi = *(const float4*)(bias + ocb);
        float bia[4] = {bi.x, bi.y, bi.z, bi.w};
        #pragma unroll
        for (int nt = 0; nt < 4; ++nt) {
            int xl = colbase + nt * 16 + pl;
            ushort4 pk;
            float v0 = acc[mt][nt][0] + bia[0]; pk.x = f2bs(v0 >= 0.f ? v0 : 0.01f * v0);
            float v1 = acc[mt][nt][1] + bia[1]; pk.y = f2bs(v1 >= 0.f ? v1 : 0.01f * v1);
            float v2 = acc[mt][nt][2] + bia[2]; pk.z = f2bs(v2 >= 0.f ? v2 : 0.01f * v2);
            float v3 = acc[mt][nt][3] + bia[3]; pk.w = f2bs(v3 >= 0.f ? v3 : 0.01f * v3);
            *(ushort4*)(out + (((size_t)(b * H + yout)) * W + xl) * C + ocb) = pk;
        }
    }
}

// =================== 3x3 conv v3 (kept for the 64-ch idwt conv) ===================
template <int C, int NPX, int WPG>
__global__ __launch_bounds__(256) void conv3_v3(
        const short* __restrict__ in, const short* __restrict__ wF,
        const float* __restrict__ bias, short* __restrict__ out,
        int H, int W) {
    constexpr int Wp = NPX + 2;
    constexpr int NCH = C / 16;
    constexpr int UNITS = 3 * Wp * 2;
    constexpr int UPT = (UNITS + 255) / 256;
    constexpr int BUFSZ = 3 * Wp * 16;
    extern __shared__ __align__(16) short inS[];

    int tid = threadIdx.x;
    int lane = tid & 63, wv = tid >> 6;
    int q = lane >> 4, pl = lane & 15;
    int ocg = wv / WPG;
    int pxoff = (wv % WPG) * 64;
    int x0 = blockIdx.x * NPX;
    int y = blockIdx.y;
    int b = blockIdx.z;

    int gbase[UPT];
    int ldsoff[UPT];
    #pragma unroll
    for (int k2 = 0; k2 < UPT; ++k2) {
        int u = k2 * 256 + tid;
        if (u < UNITS) {
            int r = u / (Wp * 2);
            int rem = u - r * (Wp * 2);
            int px = rem >> 1, hf = rem & 1;
            int ry = y - 1 + r;
            if (ry < 0) ry = 1;
            if (ry >= H) ry = H - 2;
            int rx = x0 - 1 + px;
            if (rx < 0) rx = 1;
            if (rx >= W) rx = W - 2;
            gbase[k2] = ((b * H + ry) * W + rx) * C + hf * 8;
            ldsoff[k2] = (r * Wp + px) * 16 + hf * 8;
        } else { gbase[k2] = 0; ldsoff[k2] = -1; }
    }

    f32x4 acc[4][4];
    #pragma unroll
    for (int mt = 0; mt < 4; ++mt)
        #pragma unroll
        for (int nt = 0; nt < 4; ++nt)
            acc[mt][nt] = (f32x4){0.f, 0.f, 0.f, 0.f};

    uint4 pf[UPT];
    #pragma unroll
    for (int k2 = 0; k2 < UPT; ++k2)
        if (ldsoff[k2] >= 0) pf[k2] = *(const uint4*)(in + gbase[k2]);
    #pragma unroll
    for (int k2 = 0; k2 < UPT; ++k2)
        if (ldsoff[k2] >= 0) *(uint4*)(inS + ldsoff[k2]) = pf[k2];
    __syncthreads();

    #pragma unroll 1
    for (int ch = 0; ch < NCH; ++ch) {
        const short* buf = inS + (ch & 1) * BUFSZ;
        short* nbuf = inS + ((ch + 1) & 1) * BUFSZ;
        bool more = (ch + 1 < NCH);
        const short* wbase = wF + ((size_t)(ocg * NCH + ch) * 5) * 2048;
        short8 wreg[5][4];
        #pragma unroll
        for (int pr = 0; pr < 5; ++pr)
            #pragma unroll
            for (int mt = 0; mt < 4; ++mt)
                wreg[pr][mt] = *(const short8*)(wbase + (pr * 4 + mt) * 512 + lane * 8);
        if (more) {
            #pragma unroll
            for (int k2 = 0; k2 < UPT; ++k2)
                if (ldsoff[k2] >= 0) pf[k2] = *(const uint4*)(in + gbase[k2] + (ch + 1) * 16);
        }
        #pragma unroll
        for (int pr = 0; pr < 5; ++pr) {
            int t1 = 2 * pr + (q >> 1);
            if (t1 > 8) t1 = 8;
            int ti = (t1 >= 6) ? 2 : ((t1 >= 3) ? 1 : 0);
            int tj = t1 - ti * 3;
            #pragma unroll
            for (int nt = 0; nt < 4; ++nt) {
                int i = pxoff + nt * 16 + pl + tj;
                short8 bfr = *(const short8*)(buf + (ti * Wp + i) * 16 + (q & 1) * 8);
                #pragma unroll
                for (int mt = 0; mt < 4; ++mt)
                    acc[mt][nt] = __builtin_amdgcn_mfma_f32_16x16x32_bf16(wreg[pr][mt], bfr, acc[mt][nt], 0, 0, 0);
            }
        }
        if (more) {
            #pragma unroll
            for (int k2 = 0; k2 < UPT; ++k2)
                if (ldsoff[k2] >= 0) *(uint4*)(nbuf + ldsoff[k2]) = pf[k2];
            __syncthreads();
        }
    }

    #pragma unroll
    for (int mt = 0; mt < 4; ++mt) {
        int ocb = ocg * 64 + mt * 16 + q * 4;
        float4 bi = *(const float4*)(bias + ocb);
        float bia[4] = {bi.x, bi.y, bi.z, bi.w};
        #pragma unroll
        for (int nt = 0; nt < 4; ++nt) {
            int xl = x0 + pxoff + nt * 16 + pl;
            ushort4 pk;
            float v0 = acc[mt][nt][0] + bia[0]; pk.x = f2bs(v0 >= 0.f ? v0 : 0.01f * v0);
            float v1 = acc[mt][nt][1] + bia[1]; pk.y = f2bs(v1 >= 0.f ? v1 : 0.01f * v1);
            float v2 = acc[mt][nt][2] + bia[2]; pk.z = f2bs(v2 >= 0.f ? v2 : 0.01f * v2);
            float v3 = acc[mt][nt][3] + bia[3]; pk.w = f2bs(v3 >= 0.f ? v3 : 0.01f * v3);
            *(ushort4*)(out + (((size_t)(b * H + y)) * W + xl) * C + ocb) = pk;
        }
    }
}

// =================== K conv 1x1 MFMA ===================
__global__ __launch_bounds__(256) void kconv_mfma(
        const short* __restrict__ in, const short* __restrict__ wF,
        const float* __restrict__ bias, short* __restrict__ outK) {
    __shared__ short inS[8192];
    int tid = threadIdx.x;
    int lane = tid & 63, wv = tid >> 6;
    int q = lane >> 4, pl = lane & 15;
    int ocblk = blockIdx.x;
    int m0 = blockIdx.y * 256;
    int b = blockIdx.z;
    int px0w = wv * 64;
    f32x4 acc[4][4];
    #pragma unroll
    for (int mt = 0; mt < 4; ++mt)
        #pragma unroll
        for (int nt = 0; nt < 4; ++nt)
            acc[mt][nt] = (f32x4){0.f, 0.f, 0.f, 0.f};

    for (int ch = 0; ch < 8; ++ch) {
        if (ch) __syncthreads();
        const short* src = in + ((size_t)(b * 16384 + m0)) * 256 + ch * 32;
        for (int t = tid; t < 1024; t += 256) {
            int pix = t >> 2, hf = t & 3;
            *(uint4*)(inS + pix * 32 + hf * 8) = *(const uint4*)(src + (size_t)pix * 256 + hf * 8);
        }
        short8 af[4];
        #pragma unroll
        for (int mt = 0; mt < 4; ++mt)
            af[mt] = *(const short8*)(wF + ((size_t)(ocblk * 8 + ch)) * 2048 + mt * 512 + lane * 8);
        __syncthreads();
        #pragma unroll
        for (int nt = 0; nt < 4; ++nt) {
            short8 bfr = *(const short8*)(inS + (px0w + nt * 16 + pl) * 32 + q * 8);
            #pragma unroll
            for (int mt = 0; mt < 4; ++mt)
                acc[mt][nt] = __builtin_amdgcn_mfma_f32_16x16x32_bf16(af[mt], bfr, acc[mt][nt], 0, 0, 0);
        }
    }
    #pragma unroll
    for (int mt = 0; mt < 4; ++mt) {
        int ocb = ocblk * 64 + mt * 16 + q * 4;
        float4 bi = *(const float4*)(bias + ocb);
        float bia[4] = {bi.x, bi.y, bi.z, bi.w};
        #pragma unroll
        for (int nt = 0; nt < 4; ++nt) {
            int n = m0 + px0w + nt * 16 + pl;
            #pragma unroll
            for (int r = 0; r < 4; ++r) {
                int co = ocb + r;
                outK[((size_t)(b * 64 + (co >> 2))) * 65536 + (co & 3) * 16384 + n] =
                    (short)f2bs(acc[mt][nt][r] + bia[r]);
            }
        }
    }
}

// =================== Gram via MFMA: per-head 16x16 Q.K^T + row norms ===================
__global__ __launch_bounds__(256) void gram_mfma(
        const short* __restrict__ Q, const short* __restrict__ K,
        float* __restrict__ qss, float* __restrict__ kss, float* __restrict__ gram) {
    int tid = threadIdx.x;
    int lane = tid & 63, h = tid >> 6;
    int q = lane >> 4, m = lane & 15;
    int b = blockIdx.y;
    int n0 = blockIdx.x * 512;
    const short* qrow = Q + ((size_t)(b * 64 + h * 16 + m)) * 65536 + n0 + q * 8;
    const short* krow = K + ((size_t)(b * 64 + h * 16 + m)) * 65536 + n0 + q * 8;
    f32x4 acc = (f32x4){0.f, 0.f, 0.f, 0.f};
    float sq = 0.f, sk = 0.f;
    #pragma unroll 4
    for (int it = 0; it < 16; ++it) {
        short8 aq = *(const short8*)(qrow + it * 32);
        short8 ak = *(const short8*)(krow + it * 32);
        acc = __builtin_amdgcn_mfma_f32_16x16x32_bf16(aq, ak, acc, 0, 0, 0);
        #pragma unroll
        for (int j = 0; j < 8; ++j) {
            float fq = bs2f((u16)aq[j]);
            float fk = bs2f((u16)ak[j]);
            sq += fq * fq;
            sk += fk * fk;
        }
    }
    sq += __shfl_xor(sq, 16); sq += __shfl_xor(sq, 32);
    sk += __shfl_xor(sk, 16); sk += __shfl_xor(sk, 32);
    if (q == 0) {
        atomicAdd(&qss[b * 64 + h * 16 + m], sq);
        atomicAdd(&kss[b * 64 + h * 16 + m], sk);
    }
    #pragma unroll
    for (int r = 0; r < 4; ++r) {
        int c = q * 4 + r;   // row of D
        atomicAdd(&gram[b * 1024 + h * 256 + c * 16 + m], acc[r]);
    }
}

// =================== softmax(cos-sim * temp) ===================
__global__ void attn_kernel(const float* __restrict__ gram, const float* __restrict__ qss,
                            const float* __restrict__ kss, const float* __restrict__ temp,
                            float* __restrict__ attn) {
    int bh = blockIdx.x;
    int b = bh >> 2, h = bh & 3;
    int tid = threadIdx.x;
    __shared__ float L[16][17];
    __shared__ float rowmax[16], rowsum[16];
    int c = tid >> 4, d = tid & 15;
    float qn = fmaxf(sqrtf(qss[b * 64 + h * 16 + c]), 1e-12f);
    float kn = fmaxf(sqrtf(kss[b * 64 + h * 16 + d]), 1e-12f);
    float lg = gram[b * 1024 + h * 256 + c * 16 + d] / (qn * kn) * temp[h];
    L[c][d] = lg;
    __syncthreads();
    if (tid < 16) {
        float m = -1e30f;
        for (int j = 0; j < 16; ++j) m = fmaxf(m, L[tid][j]);
        rowmax[tid] = m;
    }
    __syncthreads();
    float e = expf(lg - rowmax[c]);
    L[c][d] = e;
    __syncthreads();
    if (tid < 16) {
        float s = 0.f;
        for (int j = 0; j < 16; ++j) s += L[tid][j];
        rowsum[tid] = s;
    }
    __syncthreads();
    attn[b * 1024 + h * 256 + c * 16 + d] = e / rowsum[c];
}

// =================== fold v2 ===================
__global__ __launch_bounds__(256) void fold_v2(
        const float* __restrict__ attn, const float* __restrict__ w3,
        const float* __restrict__ b3, const float* __restrict__ wproj,
        short* __restrict__ WfoldF, float* __restrict__ bfold) {
    __shared__ float attn_s[1024];
    __shared__ float wp_s[64][65];
    __shared__ float Aeff_s[64][17];
    __shared__ float beff[64];
    int bt = blockIdx.y;
    int b = bt >> 2, t = bt & 3;
    int ci0 = blockIdx.x * 16;
    int tid = threadIdx.x;
    for (int i = 0; i < 4; ++i) attn_s[tid + i * 256] = attn[b * 1024 + tid + i * 256];
    #pragma unroll
    for (int i = 0; i < 16; ++i) {
        int idx = tid + i * 256;
        int co = idx >> 6, C = idx & 63;
        wp_s[co][C] = wproj[co * 128 + C];
    }
    __syncthreads();
    #pragma unroll
    for (int pass = 0; pass < 4; ++pass) {
        int el = pass * 256 + tid;
        int C = el >> 4, ci_l = el & 15;
        int h = C >> 4, c = C & 15;
        float s = 0.f;
        #pragma unroll
        for (int d = 0; d < 16; ++d)
            s += attn_s[h * 256 + c * 16 + d] * w3[(size_t)(4 * (h * 16 + d) + t) * 256 + ci0 + ci_l];
        Aeff_s[C][ci_l] = s;
    }
    if (blockIdx.x == 0 && tid < 64) {
        int h = tid >> 4, c = tid & 15;
        float s = 0.f;
        #pragma unroll
        for (int d = 0; d < 16; ++d)
            s += attn_s[h * 256 + c * 16 + d] * b3[4 * (h * 16 + d) + t];
        beff[tid] = s;
    }
    __syncthreads();
    #pragma unroll
    for (int pass = 0; pass < 4; ++pass) {
        int el = pass * 256 + tid;
        int ci_l = el >> 6, co = el & 63;
        float s = 0.f;
        #pragma unroll
        for (int C = 0; C < 64; ++C) s += wp_s[co][C] * Aeff_s[C][ci_l];
        int ci = ci0 + ci_l;
        int chk = ci >> 5;
        int s5 = ci & 31;
        int j = s5 & 7;
        int lane2 = (((s5 >> 3) << 4)) | (co & 15);
        int mt = co >> 4;
        WfoldF[(((size_t)(bt * 8 + chk) * 4 + mt)) * 512 + lane2 * 8 + j] = (short)f2bs(s);
    }
    if (blockIdx.x == 0 && tid < 64) {
        float s = 0.f;
        #pragma unroll
        for (int C = 0; C < 64; ++C) s += wp_s[tid][C] * beff[C];
        bfold[bt * 64 + tid] = s;
    }
}

// =================== final: out = Wfold[b,t]·D1 + bfold + Wp2·I2, fp32 out ===================
__global__ __launch_bounds__(256) void final_mfma(
        const short* __restrict__ D1, const short* __restrict__ I2,
        const short* __restrict__ WfoldF, const short* __restrict__ wpF,
        const float* __restrict__ bfold, float* __restrict__ out) {
    __shared__ short inS[8192];
    int tid = threadIdx.x;
    int lane = tid & 63, wv = tid >> 6;
    int q = lane >> 4, pl = lane & 15;
    int n0 = blockIdx.x * 256;
    int b = blockIdx.y;
    int t = n0 >> 14, m0 = n0 & 16383, bt = b * 4 + t;
    int px0w = wv * 64;
    f32x4 acc[4][4];
    #pragma unroll
    for (int mt = 0; mt < 4; ++mt) {
        float4 bf4 = *(const float4*)(bfold + bt * 64 + mt * 16 + q * 4);
        #pragma unroll
        for (int nt = 0; nt < 4; ++nt)
            acc[mt][nt] = (f32x4){bf4.x, bf4.y, bf4.z, bf4.w};
    }
    for (int ch = 0; ch < 8; ++ch) {
        if (ch) __syncthreads();
        const short* src = D1 + ((size_t)(b * 16384 + m0)) * 256 + ch * 32;
        for (int tt = tid; tt < 1024; tt += 256) {
            int pix = tt >> 2, hf = tt & 3;
            *(uint4*)(inS + pix * 32 + hf * 8) = *(const uint4*)(src + (size_t)pix * 256 + hf * 8);
        }
        short8 af[4];
        #pragma unroll
        for (int mt = 0; mt < 4; ++mt)
            af[mt] = *(const short8*)(WfoldF + ((size_t)(bt * 8 + ch)) * 2048 + mt * 512 + lane * 8);
        __syncthreads();
        #pragma unroll
        for (int nt = 0; nt < 4; ++nt) {
            short8 bfr = *(const short8*)(inS + (px0w + nt * 16 + pl) * 32 + q * 8);
            #pragma unroll
            for (int mt = 0; mt < 4; ++mt)
                acc[mt][nt] = __builtin_amdgcn_mfma_f32_16x16x32_bf16(af[mt], bfr, acc[mt][nt], 0, 0, 0);
        }
    }
    for (int ch = 0; ch < 2; ++ch) {
        __syncthreads();
        const short* src = I2 + ((size_t)(b * 65536 + n0)) * 64 + ch * 32;
        for (int tt = tid; tt < 1024; tt += 256) {
            int pix = tt >> 2, hf = tt & 3;
            *(uint4*)(inS + pix * 32 + hf * 8) = *(const uint4*)(src + (size_t)pix * 64 + hf * 8);
        }
        short8 af[4];
        #pragma unroll
        for (int mt = 0; mt < 4; ++mt)
            af[mt] = *(const short8*)(wpF + (size_t)ch * 2048 + mt * 512 + lane * 8);
        __syncthreads();
        #pragma unroll
        for (int nt = 0; nt < 4; ++nt) {
            short8 bfr = *(const short8*)(inS + (px0w + nt * 16 + pl) * 32 + q * 8);
            #pragma unroll
            for (int mt = 0; mt < 4; ++mt)
                acc[mt][nt] = __builtin_amdgcn_mfma_f32_16x16x32_bf16(af[mt], bfr, acc[mt][nt], 0, 0, 0);
        }
    }
    #pragma unroll
    for (int mt = 0; mt < 4; ++mt) {
        #pragma unroll
        for (int nt = 0; nt < 4; ++nt) {
            int n = n0 + px0w + nt * 16 + pl;
            #pragma unroll
            for (int r = 0; r < 4; ++r) {
                int co = mt * 16 + q * 4 + r;
                out[((size_t)(b * 64 + co)) * 65536 + n] = acc[mt][nt][r];
            }
        }
    }
}

extern "C" void kernel_launch(void* const* d_in, const int* in_sizes, int n_in,
                              void* d_out, int out_size, void* d_ws, size_t ws_size,
                              hipStream_t stream) {
    const float* x     = (const float*)d_in[0];
    const float* temp  = (const float*)d_in[1];
    const float* w1    = (const float*)d_in[2];
    const float* b1    = (const float*)d_in[3];
    const float* w2    = (const float*)d_in[4];
    const float* b2    = (const float*)d_in[5];
    const float* w3    = (const float*)d_in[6];
    const float* b3    = (const float*)d_in[7];
    const float* wdwt  = (const float*)d_in[8];
    const float* bdwt  = (const float*)d_in[9];
    const float* widwt = (const float*)d_in[10];
    const float* bidwt = (const float*)d_in[11];
    const float* wproj = (const float*)d_in[12];
    float* out = (float*)d_out;

    char* W8 = (char*)d_ws;
    const size_t SLOT = 16777216;
    short* slotA = (short*)(W8);              // D0 -> I0
    short* slotB = (short*)(W8 + SLOT);       // D1
    short* slotC = (short*)(W8 + 2 * SLOT);   // Qb -> I2
    short* slotD = (short*)(W8 + 3 * SLOT);   // Kb
    char* P = W8 + 4 * SLOT;
    short* wF1    = (short*)P; P += 2 * 655360;
    short* wF2c   = (short*)P; P += 2 * 40960;
    short* wFk    = (short*)P; P += 2 * 65536;
    short* wpF    = (short*)P; P += 2 * 4096;
    short* wFq    = (short*)P; P += 2 * 4096;
    short* WfoldF = (short*)P; P += 2 * 131072;
    float* scr    = (float*)P;
    float* qss   = scr;
    float* kss   = scr + 128;
    float* gram  = scr + 256;
    float* attn  = scr + 2304;
    float* bfold = scr + 4352;

    prep_all<<<3009, 256, 0, stream>>>(wdwt, widwt, w2, wproj, w1,
                                       wF1, wF2c, wFk, wpF, wFq, scr);

    // fused DWT + Q conv (x read once): D0 -> slotA, Qb -> slotC
    dwtq_kernel<<<dim3(2, 128, 2), 256, 0, stream>>>(x, wFq, b1, slotA, slotC);

    // DWT-branch 3x3 conv — v11: per-wave register-dbuf weights, no weight DMA/LDS
    conv3_v11<<<dim3(64, 4, 2), 256, 0, stream>>>(slotA, wF1, bdwt, slotB);

    // K conv + gram (frees slotC after gram)
    kconv_mfma<<<dim3(4, 64, 2), 256, 0, stream>>>(slotB, wFk, b2, slotD);
    gram_mfma<<<dim3(128, 2), 256, 0, stream>>>(slotC, slotD, qss, kss, gram);

    // IDWT branch (slotA reused for I0, slotC reused for I2)
    idwt_kernel<<<8192, 256, 0, stream>>>(slotB, slotA);
    conv3_v3<64, 256, 4><<<dim3(1, 256, 2), 256, 49536, stream>>>(slotA, wF2c, bidwt, slotC, 256, 256);

    // softmax -> fold
    attn_kernel<<<8, 256, 0, stream>>>(gram, qss, kss, temp, attn);
    fold_v2<<<dim3(16, 8), 256, 0, stream>>>(attn, w3, b3, wproj, WfoldF, bfold);

    // fused (attn·V + proj) + idwt-branch proj
    final_mfma<<<dim3(256, 2), 256, 0, stream>>>(slotB, slotC, WfoldF, wpF, bfold, out);
}

// Round 9
// 254.996 us; speedup vs baseline: 1.1591x; 1.1399x over previous
//
#include <hip/hip_runtime.h>
#include <hip/hip_bf16.h>

typedef __hip_bfloat16 bf16;
typedef __attribute__((ext_vector_type(8))) short short8;
typedef __attribute__((ext_vector_type(4))) float f32x4;
typedef unsigned short u16;
typedef unsigned int u32;

static __device__ __forceinline__ u16 f2bs(float f) {
    bf16 h = __float2bfloat16(f);
    return *reinterpret_cast<u16*>(&h);
}
static __device__ __forceinline__ float bs2f(u16 u) {
    union { float f; u32 i; } x; x.i = ((u32)u) << 16; return x.f;
}
static __device__ __forceinline__ uint4 pack8(const u16* p) {
    uint4 v;
    v.x = (u32)p[0] | ((u32)p[1] << 16);
    v.y = (u32)p[2] | ((u32)p[3] << 16);
    v.z = (u32)p[4] | ((u32)p[5] << 16);
    v.w = (u32)p[6] | ((u32)p[7] << 16);
    return v;
}
// async global->LDS DMA, 16B per lane. Per-lane GLOBAL address, wave-uniform LDS base.
static __device__ __forceinline__ void gl16(const short* g, short* l) {
    __builtin_amdgcn_global_load_lds(
        (const __attribute__((address_space(1))) u32*)(g),
        (__attribute__((address_space(3))) u32*)(l), 16, 0, 0);
}

// =================== weight prep ===================
// classic layout [ocblk][ch][pr][mt][lane][j] — for ocblk=1 (C=64) this is already
// phase-major: phase P=(ch*5+pr) at offset P*2048 shorts (used by conv3_v12)
__device__ __forceinline__ void prep3_body(const float* __restrict__ w, short* __restrict__ wF,
                                           int C, int idx) {
    int j = idx & 7;
    int lane = (idx >> 3) & 63;
    int mt = (idx >> 9) & 3;
    int rest = idx >> 11;
    int pair = rest % 5;
    int bo = rest / 5;
    int nchunks = C / 16;
    int ch = bo % nchunks;
    int ocblk = bo / nchunks;
    int s = ((lane >> 4) * 8 + j);
    int tp = 2 * pair + (s >> 4);
    int ci = ch * 16 + (s & 15);
    int oc = ocblk * 64 + mt * 16 + (lane & 15);
    float v = (tp <= 8) ? w[((size_t)(oc * C + ci)) * 9 + tp] : 0.f;
    wF[idx] = (short)f2bs(v);
}
// phase-major layout [ch][pr][ocg][mt][lane][j] for conv3_v11 (4KB per (phase,ocg))
__device__ __forceinline__ void prep3_chpr(const float* __restrict__ w, short* __restrict__ wF,
                                           int idx) {
    int j = idx & 7;
    int lane = (idx >> 3) & 63;
    int mt = (idx >> 9) & 3;
    int rest = idx >> 11;
    int ocg = rest & 3;
    int r2 = rest >> 2;
    int pr = r2 % 5;
    int ch = r2 / 5;
    int s = ((lane >> 4) * 8 + j);
    int tp = 2 * pr + (s >> 4);
    int ci = ch * 16 + (s & 15);
    int oc = ocg * 64 + mt * 16 + (lane & 15);
    float v = (tp <= 8) ? w[((size_t)(oc * 256 + ci)) * 9 + tp] : 0.f;
    wF[idx] = (short)f2bs(v);
}
__device__ __forceinline__ void prep1_body(const float* __restrict__ w, short* __restrict__ wF,
                                           int Cin, int cioff, int nchunks, int idx) {
    int j = idx & 7;
    int lane = (idx >> 3) & 63;
    int mt = (idx >> 9) & 3;
    int bo = idx >> 11;
    int ch = bo % nchunks;
    int ocblk = bo / nchunks;
    int s = (lane >> 4) * 8 + j;
    int ci = cioff + ch * 32 + s;
    int oc = ocblk * 64 + mt * 16 + (lane & 15);
    wF[idx] = (short)f2bs(w[(size_t)oc * Cin + ci]);
}

__global__ __launch_bounds__(256) void prep_all(
        const float* __restrict__ wdwt, const float* __restrict__ widwt,
        const float* __restrict__ w2, const float* __restrict__ wproj,
        const float* __restrict__ w1,
        short* __restrict__ wF1, short* __restrict__ wF2c, short* __restrict__ wFk,
        short* __restrict__ wpF, short* __restrict__ wFq, float* __restrict__ scr) {
    int blk = blockIdx.x;
    int tid = threadIdx.x;
    if (blk < 2560) {
        prep3_chpr(wdwt, wF1, blk * 256 + tid);
    } else if (blk < 2720) {
        prep3_body(widwt, wF2c, 64, (blk - 2560) * 256 + tid);
    } else if (blk < 2976) {
        prep1_body(w2, wFk, 256, 0, 8, (blk - 2720) * 256 + tid);
    } else if (blk < 2992) {
        prep1_body(wproj, wpF, 128, 64, 2, (blk - 2976) * 256 + tid);
    } else if (blk < 3008) {
        prep1_body(w1, wFq, 64, 0, 2, (blk - 2992) * 256 + tid);
    } else {
        for (int i = tid; i < 4864; i += 256) scr[i] = 0.f;
    }
}

// =================== fused Haar DWT + Q conv ===================
__global__ __launch_bounds__(256) void dwtq_kernel(
        const float* __restrict__ x, const short* __restrict__ wFq,
        const float* __restrict__ b1, short* __restrict__ d0, short* __restrict__ outQ) {
    __shared__ short ls[256 * 72];
    int tid = threadIdx.x;
    int lane = tid & 63, wv = tid >> 6;
    int q = lane >> 4, pl = lane & 15;
    int xh = blockIdx.x;
    int y2 = blockIdx.y;
    int b = blockIdx.z;
    int x0 = xh * 128;

    #pragma unroll
    for (int k2 = 0; k2 < 16; ++k2) {
        int u = k2 * 256 + tid;
        int ch = u & 63;
        int xu = (u >> 6) & 31;
        int r = (u >> 11) & 1;
        float4 v = *(const float4*)(x + (((size_t)(b * 64 + ch) * 256 + (2 * y2 + r))) * 256 + x0 + xu * 4);
        ls[(r * 128 + xu * 4 + 0) * 72 + ch] = (short)f2bs(v.x);
        ls[(r * 128 + xu * 4 + 1) * 72 + ch] = (short)f2bs(v.y);
        ls[(r * 128 + xu * 4 + 2) * 72 + ch] = (short)f2bs(v.z);
        ls[(r * 128 + xu * 4 + 3) * 72 + ch] = (short)f2bs(v.w);
    }
    __syncthreads();

    f32x4 acc[4][4];
    #pragma unroll
    for (int mt = 0; mt < 4; ++mt)
        #pragma unroll
        for (int nt = 0; nt < 4; ++nt)
            acc[mt][nt] = (f32x4){0.f, 0.f, 0.f, 0.f};
    #pragma unroll
    for (int chk = 0; chk < 2; ++chk) {
        short8 af[4];
        #pragma unroll
        for (int mt = 0; mt < 4; ++mt)
            af[mt] = *(const short8*)(wFq + (chk * 4 + mt) * 512 + lane * 8);
        #pragma unroll
        for (int nt = 0; nt < 4; ++nt) {
            int p = wv * 64 + nt * 16 + pl;
            short8 bfr = *(const short8*)(ls + p * 72 + chk * 32 + q * 8);
            #pragma unroll
            for (int mt = 0; mt < 4; ++mt)
                acc[mt][nt] = __builtin_amdgcn_mfma_f32_16x16x32_bf16(af[mt], bfr, acc[mt][nt], 0, 0, 0);
        }
    }
    #pragma unroll
    for (int mt = 0; mt < 4; ++mt) {
        int ocb = mt * 16 + q * 4;
        float4 bi = *(const float4*)(b1 + ocb);
        float bia[4] = {bi.x, bi.y, bi.z, bi.w};
        #pragma unroll
        for (int nt = 0; nt < 4; ++nt) {
            int p = wv * 64 + nt * 16 + pl;
            int n = (2 * y2 + (p >> 7)) * 256 + x0 + (p & 127);
            #pragma unroll
            for (int r = 0; r < 4; ++r)
                outQ[((size_t)(b * 64 + ocb + r)) * 65536 + n] = (short)f2bs(acc[mt][nt][r] + bia[r]);
        }
    }

    int xl = tid >> 2;
    int cg = tid & 3;
    int c0 = cg * 16;
    u16 obuf[4][16];
    #pragma unroll
    for (int cl = 0; cl < 16; ++cl) {
        int c = c0 + cl;
        float a  = bs2f(ls[(2 * xl) * 72 + c]);
        float bb = bs2f(ls[(2 * xl + 1) * 72 + c]);
        float c2 = bs2f(ls[(128 + 2 * xl) * 72 + c]);
        float dd = bs2f(ls[(128 + 2 * xl + 1) * 72 + c]);
        obuf[0][cl] = f2bs((a - bb + c2 - dd) * 0.5f);  // lh
        obuf[1][cl] = f2bs((a + bb - c2 - dd) * 0.5f);  // hl
        obuf[2][cl] = f2bs((a - bb - c2 + dd) * 0.5f);  // hh
        obuf[3][cl] = f2bs((a + bb + c2 + dd) * 0.5f);  // ll
    }
    int xd = xh * 64 + xl;
    size_t P = ((size_t)(b * 128 + y2) * 128 + xd) * 256;
    #pragma unroll
    for (int g = 0; g < 4; ++g) {
        *(uint4*)&d0[P + g * 64 + c0]     = pack8(&obuf[g][0]);
        *(uint4*)&d0[P + g * 64 + c0 + 8] = pack8(&obuf[g][8]);
    }
}

// =================== Haar IDWT ===================
__global__ __launch_bounds__(256) void idwt_kernel(const short* __restrict__ d1, short* __restrict__ i0) {
    int tid = threadIdx.x;
    int lane = tid & 63;
    int p = blockIdx.x * 4 + (tid >> 6);
    int b = p >> 14, m = p & 16383;
    ushort4 v = *(const ushort4*)(d1 + ((size_t)(b * 16384 + m)) * 256 + 4 * lane);
    float yl = bs2f(v.x), lh = bs2f(v.y), hl = bs2f(v.z), hh = bs2f(v.w);
    float a_ = (yl + lh + hl + hh) * 0.5f;
    float b_ = (yl - lh + hl - hh) * 0.5f;
    float c_ = (yl + lh - hl - hh) * 0.5f;
    float d_ = (yl - lh - hl + hh) * 0.5f;
    int y = m >> 7, xx = m & 127;
    u16* o = (u16*)i0;
    size_t base = ((size_t)(b * 256 + 2 * y) * 256 + 2 * xx) * 64 + lane;
    o[base] = f2bs(a_);
    o[base + 64] = f2bs(b_);
    o[base + 256 * 64] = f2bs(c_);
    o[base + 256 * 64 + 64] = f2bs(d_);
}

// =================== 3x3 conv v11 (C=256, H=W=128): reg-dbuf weights, no weight LDS ===
#define PHASE_V11(P, WC, WN)                                                      \
    {                                                                             \
        const int P_ = (P);                                                       \
        const int ch_ = P_ / 5;                                                   \
        const int pr_ = P_ - ch_ * 5;                                             \
        if (P_ + 1 < 80) {                                                        \
            const short* wn = wF + ((size_t)((P_ + 1) * 4 + ocg)) * 2048;         \
            _Pragma("unroll")                                                     \
            for (int mt = 0; mt < 4; ++mt)                                        \
                WN[mt] = *(const short8*)(wn + mt * 512 + lane * 8);              \
        }                                                                         \
        if (pr_ == 0 && ch_ < 15) {                                               \
            short* id = ibuf[(ch_ + 1) & 1];                                      \
            _Pragma("unroll")                                                     \
            for (int k2 = 0; k2 < UPT; ++k2)                                      \
                if (act[k2]) gl16(gp[k2] + (ch_ + 1) * 16, id + ibo[k2]);         \
        }                                                                         \
        const short* ib = ibuf[ch_ & 1];                                          \
        int t1 = 2 * pr_ + (q >> 1);                                              \
        if (t1 > 8) t1 = 8;                                                       \
        int ti = (t1 >= 6) ? 2 : ((t1 >= 3) ? 1 : 0);                             \
        int tj = t1 - ti * 3;                                                     \
        _Pragma("unroll")                                                         \
        for (int nt = 0; nt < 4; ++nt) {                                          \
            int i = colbase + nt * 16 + pl + tj;                                  \
            short8 bfr = *(const short8*)(ib + ((ti + orow) * Wp + i) * 16 + (q & 1) * 8); \
            _Pragma("unroll")                                                     \
            for (int mt = 0; mt < 4; ++mt)                                        \
                acc[mt][nt] = __builtin_amdgcn_mfma_f32_16x16x32_bf16(WC[mt], bfr, acc[mt][nt], 0, 0, 0); \
        }                                                                         \
        __syncthreads();                                                          \
    }

__global__ __launch_bounds__(256) void conv3_v11(
        const short* __restrict__ in, const short* __restrict__ wF,
        const float* __restrict__ bias, short* __restrict__ out) {
    constexpr int C = 256, W = 128, H = 128;
    constexpr int Wp = W + 2;              // 130 staged cols
    constexpr int UNITS = 4 * Wp * 2;      // 1040 16B-units per input chunk (4 rows)
    constexpr int UPT = 5;                 // ceil(1040/256)
    __shared__ short ibuf[2][4 * Wp * 16]; // 2 x 16.64 KB (input only; weights in regs)

    int tid = threadIdx.x;
    int lane = tid & 63, wv = tid >> 6;
    int q = lane >> 4, pl = lane & 15;
    int ocg = blockIdx.y;
    int bx = blockIdx.x;                   // row-pair index 0..63
    int rp = ((bx & 7) << 3) | (bx >> 3);  // bijective 8x8: XCD k owns row-pairs [8k,8k+8)
    int y0 = rp * 2;
    int b = blockIdx.z;
    int orow = wv >> 1;                    // which of the 2 output rows
    int colbase = (wv & 1) * 64;           // which 64-px half

    const short* gp[UPT];
    int ibo[UPT];
    bool act[UPT];
    #pragma unroll
    for (int k2 = 0; k2 < UPT; ++k2) {
        int u = k2 * 256 + tid;
        act[k2] = (u < UNITS);
        int uu = act[k2] ? u : 0;
        int r = uu / (Wp * 2);
        int rem = uu - r * (Wp * 2);
        int px = rem >> 1, hf = rem & 1;
        int ry = y0 - 1 + r;
        if (ry < 0) ry = 1;
        if (ry >= H) ry = 2 * H - 2 - ry;
        int rx = px - 1;
        if (rx < 0) rx = 1;
        if (rx >= W) rx = W - 2;
        gp[k2] = in + ((b * H + ry) * W + rx) * C + hf * 8;
        ibo[k2] = (k2 * 256 + wv * 64) * 8;   // wave-uniform LDS base (lane*16B auto)
    }

    f32x4 acc[4][4];
    #pragma unroll
    for (int mt = 0; mt < 4; ++mt)
        #pragma unroll
        for (int nt = 0; nt < 4; ++nt)
            acc[mt][nt] = (f32x4){0.f, 0.f, 0.f, 0.f};

    short8 wA[4], wB[4];
    {
        const short* w0 = wF + ((size_t)(0 * 4 + ocg)) * 2048;
        #pragma unroll
        for (int mt = 0; mt < 4; ++mt)
            wA[mt] = *(const short8*)(w0 + mt * 512 + lane * 8);
    }
    #pragma unroll
    for (int k2 = 0; k2 < UPT; ++k2)
        if (act[k2]) gl16(gp[k2], &ibuf[0][ibo[k2]]);
    __syncthreads();

    #pragma unroll 1
    for (int P2 = 0; P2 < 80; P2 += 2) {
        PHASE_V11(P2, wA, wB)
        PHASE_V11(P2 + 1, wB, wA)
    }

    int yout = y0 + orow;
    #pragma unroll
    for (int mt = 0; mt < 4; ++mt) {
        int ocb = ocg * 64 + mt * 16 + q * 4;
        float4 bi = *(const float4*)(bias + ocb);
        float bia[4] = {bi.x, bi.y, bi.z, bi.w};
        #pragma unroll
        for (int nt = 0; nt < 4; ++nt) {
            int xl = colbase + nt * 16 + pl;
            ushort4 pk;
            float v0 = acc[mt][nt][0] + bia[0]; pk.x = f2bs(v0 >= 0.f ? v0 : 0.01f * v0);
            float v1 = acc[mt][nt][1] + bia[1]; pk.y = f2bs(v1 >= 0.f ? v1 : 0.01f * v1);
            float v2 = acc[mt][nt][2] + bia[2]; pk.z = f2bs(v2 >= 0.f ? v2 : 0.01f * v2);
            float v3 = acc[mt][nt][3] + bia[3]; pk.w = f2bs(v3 >= 0.f ? v3 : 0.01f * v3);
            *(ushort4*)(out + (((size_t)(b * H + yout)) * W + xl) * C + ocb) = pk;
        }
    }
}

// =================== 3x3 conv v12 (C=64, H=W=256): v11 structure for the idwt conv ===
// Old conv3_v3<64,256,4> was 64.5us with FETCH 123MB / WRITE 66MB (vs 17+17 ideal):
// y round-robins across XCDs so every 3-row halo is re-fetched from HBM by 3 XCDs,
// weights re-stream, partial-line writebacks. v12 = v11 schedule at C=64 geometry:
// block = 4 waves x 64 oc (all) x 2 rows x 128 cols; 20 phases (4 chunks x 5 pr);
// reg ping-pong weights (wF2c's prep3_body layout is phase-major at ocblk=1:
// phase P at +P*2048 shorts); input DMA-staged at chunk boundaries only.
// Grid (128 rp, 2 xh, 2 b): linear id = bx + 128*xh + 256*b, 128%8==0 -> XCD = bx%8;
// swizzle rp=((bx&7)<<4)|(bx>>3) gives XCD k contiguous rows [32k,32k+32) (both xh
// halves) -> halo + weights L2-local; full 128B output line per px from one wave.
#define PHASE_V12(P, WC, WN)                                                      \
    {                                                                             \
        const int P_ = (P);                                                       \
        const int ch_ = P_ / 5;                                                   \
        const int pr_ = P_ - ch_ * 5;                                             \
        if (P_ + 1 < 20) {                                                        \
            const short* wn = wF + ((size_t)(P_ + 1)) * 2048;                     \
            _Pragma("unroll")                                                     \
            for (int mt = 0; mt < 4; ++mt)                                        \
                WN[mt] = *(const short8*)(wn + mt * 512 + lane * 8);              \
        }                                                                         \
        if (pr_ == 0 && ch_ < 3) {                                                \
            short* id = ibuf[(ch_ + 1) & 1];                                      \
            _Pragma("unroll")                                                     \
            for (int k2 = 0; k2 < UPT; ++k2)                                      \
                if (act[k2]) gl16(gp[k2] + (ch_ + 1) * 16, id + ibo[k2]);         \
        }                                                                         \
        const short* ib = ibuf[ch_ & 1];                                          \
        int t1 = 2 * pr_ + (q >> 1);                                              \
        if (t1 > 8) t1 = 8;                                                       \
        int ti = (t1 >= 6) ? 2 : ((t1 >= 3) ? 1 : 0);                             \
        int tj = t1 - ti * 3;                                                     \
        _Pragma("unroll")                                                         \
        for (int nt = 0; nt < 4; ++nt) {                                          \
            int i = colbase + nt * 16 + pl + tj;                                  \
            short8 bfr = *(const short8*)(ib + ((ti + orow) * Wp + i) * 16 + (q & 1) * 8); \
            _Pragma("unroll")                                                     \
            for (int mt = 0; mt < 4; ++mt)                                        \
                acc[mt][nt] = __builtin_amdgcn_mfma_f32_16x16x32_bf16(WC[mt], bfr, acc[mt][nt], 0, 0, 0); \
        }                                                                         \
        __syncthreads();                                                          \
    }

__global__ __launch_bounds__(256) void conv3_v12(
        const short* __restrict__ in, const short* __restrict__ wF,
        const float* __restrict__ bias, short* __restrict__ out) {
    constexpr int C = 64, W = 256, H = 256;
    constexpr int Wp = 130;                // 128-col window + halo
    constexpr int UNITS = 4 * Wp * 2;      // 1040 16B-units per input chunk (4 rows)
    constexpr int UPT = 5;                 // ceil(1040/256)
    __shared__ short ibuf[2][4 * Wp * 16]; // 2 x 16.64 KB

    int tid = threadIdx.x;
    int lane = tid & 63, wv = tid >> 6;
    int q = lane >> 4, pl = lane & 15;
    int bx = blockIdx.x;                   // row-pair index 0..127
    int rp = ((bx & 7) << 4) | (bx >> 3);  // XCD k owns row-pairs [16k,16k+16)
    int y0 = rp * 2;
    int xh = blockIdx.y;
    int x0 = xh * 128;
    int b = blockIdx.z;
    int orow = wv >> 1;                    // which of the 2 output rows
    int colbase = (wv & 1) * 64;           // which 64-px half

    const short* gp[UPT];
    int ibo[UPT];
    bool act[UPT];
    #pragma unroll
    for (int k2 = 0; k2 < UPT; ++k2) {
        int u = k2 * 256 + tid;
        act[k2] = (u < UNITS);
        int uu = act[k2] ? u : 0;
        int r = uu / (Wp * 2);
        int rem = uu - r * (Wp * 2);
        int px = rem >> 1, hf = rem & 1;
        int ry = y0 - 1 + r;
        if (ry < 0) ry = 1;
        if (ry >= H) ry = 2 * H - 2 - ry;
        int rx = x0 - 1 + px;
        if (rx < 0) rx = 1;
        if (rx >= W) rx = 2 * W - 2 - rx;
        gp[k2] = in + ((b * H + ry) * W + rx) * C + hf * 8;
        ibo[k2] = (k2 * 256 + wv * 64) * 8;   // wave-uniform LDS base (lane*16B auto)
    }

    f32x4 acc[4][4];
    #pragma unroll
    for (int mt = 0; mt < 4; ++mt)
        #pragma unroll
        for (int nt = 0; nt < 4; ++nt)
            acc[mt][nt] = (f32x4){0.f, 0.f, 0.f, 0.f};

    short8 wA[4], wB[4];
    {
        #pragma unroll
        for (int mt = 0; mt < 4; ++mt)
            wA[mt] = *(const short8*)(wF + mt * 512 + lane * 8);
    }
    #pragma unroll
    for (int k2 = 0; k2 < UPT; ++k2)
        if (act[k2]) gl16(gp[k2], &ibuf[0][ibo[k2]]);
    __syncthreads();

    #pragma unroll 1
    for (int P2 = 0; P2 < 20; P2 += 2) {
        PHASE_V12(P2, wA, wB)
        PHASE_V12(P2 + 1, wB, wA)
    }

    int yout = y0 + orow;
    #pragma unroll
    for (int mt = 0; mt < 4; ++mt) {
        int ocb = mt * 16 + q * 4;
        float4 bi = *(const float4*)(bias + ocb);
        float bia[4] = {bi.x, bi.y, bi.z, bi.w};
        #pragma unroll
        for (int nt = 0; nt < 4; ++nt) {
            int xl = x0 + colbase + nt * 16 + pl;
            ushort4 pk;
            float v0 = acc[mt][nt][0] + bia[0]; pk.x = f2bs(v0 >= 0.f ? v0 : 0.01f * v0);
            float v1 = acc[mt][nt][1] + bia[1]; pk.y = f2bs(v1 >= 0.f ? v1 : 0.01f * v1);
            float v2 = acc[mt][nt][2] + bia[2]; pk.z = f2bs(v2 >= 0.f ? v2 : 0.01f * v2);
            float v3 = acc[mt][nt][3] + bia[3]; pk.w = f2bs(v3 >= 0.f ? v3 : 0.01f * v3);
            *(ushort4*)(out + (((size_t)(b * H + yout)) * W + xl) * C + ocb) = pk;
        }
    }
}

// =================== K conv 1x1 MFMA ===================
__global__ __launch_bounds__(256) void kconv_mfma(
        const short* __restrict__ in, const short* __restrict__ wF,
        const float* __restrict__ bias, short* __restrict__ outK) {
    __shared__ short inS[8192];
    int tid = threadIdx.x;
    int lane = tid & 63, wv = tid >> 6;
    int q = lane >> 4, pl = lane & 15;
    int ocblk = blockIdx.x;
    int m0 = blockIdx.y * 256;
    int b = blockIdx.z;
    int px0w = wv * 64;
    f32x4 acc[4][4];
    #pragma unroll
    for (int mt = 0; mt < 4; ++mt)
        #pragma unroll
        for (int nt = 0; nt < 4; ++nt)
            acc[mt][nt] = (f32x4){0.f, 0.f, 0.f, 0.f};

    for (int ch = 0; ch < 8; ++ch) {
        if (ch) __syncthreads();
        const short* src = in + ((size_t)(b * 16384 + m0)) * 256 + ch * 32;
        for (int t = tid; t < 1024; t += 256) {
            int pix = t >> 2, hf = t & 3;
            *(uint4*)(inS + pix * 32 + hf * 8) = *(const uint4*)(src + (size_t)pix * 256 + hf * 8);
        }
        short8 af[4];
        #pragma unroll
        for (int mt = 0; mt < 4; ++mt)
            af[mt] = *(const short8*)(wF + ((size_t)(ocblk * 8 + ch)) * 2048 + mt * 512 + lane * 8);
        __syncthreads();
        #pragma unroll
        for (int nt = 0; nt < 4; ++nt) {
            short8 bfr = *(const short8*)(inS + (px0w + nt * 16 + pl) * 32 + q * 8);
            #pragma unroll
            for (int mt = 0; mt < 4; ++mt)
                acc[mt][nt] = __builtin_amdgcn_mfma_f32_16x16x32_bf16(af[mt], bfr, acc[mt][nt], 0, 0, 0);
        }
    }
    #pragma unroll
    for (int mt = 0; mt < 4; ++mt) {
        int ocb = ocblk * 64 + mt * 16 + q * 4;
        float4 bi = *(const float4*)(bias + ocb);
        float bia[4] = {bi.x, bi.y, bi.z, bi.w};
        #pragma unroll
        for (int nt = 0; nt < 4; ++nt) {
            int n = m0 + px0w + nt * 16 + pl;
            #pragma unroll
            for (int r = 0; r < 4; ++r) {
                int co = ocb + r;
                outK[((size_t)(b * 64 + (co >> 2))) * 65536 + (co & 3) * 16384 + n] =
                    (short)f2bs(acc[mt][nt][r] + bia[r]);
            }
        }
    }
}

// =================== Gram via MFMA: per-head 16x16 Q.K^T + row norms ===================
__global__ __launch_bounds__(256) void gram_mfma(
        const short* __restrict__ Q, const short* __restrict__ K,
        float* __restrict__ qss, float* __restrict__ kss, float* __restrict__ gram) {
    int tid = threadIdx.x;
    int lane = tid & 63, h = tid >> 6;
    int q = lane >> 4, m = lane & 15;
    int b = blockIdx.y;
    int n0 = blockIdx.x * 512;
    const short* qrow = Q + ((size_t)(b * 64 + h * 16 + m)) * 65536 + n0 + q * 8;
    const short* krow = K + ((size_t)(b * 64 + h * 16 + m)) * 65536 + n0 + q * 8;
    f32x4 acc = (f32x4){0.f, 0.f, 0.f, 0.f};
    float sq = 0.f, sk = 0.f;
    #pragma unroll 4
    for (int it = 0; it < 16; ++it) {
        short8 aq = *(const short8*)(qrow + it * 32);
        short8 ak = *(const short8*)(krow + it * 32);
        acc = __builtin_amdgcn_mfma_f32_16x16x32_bf16(aq, ak, acc, 0, 0, 0);
        #pragma unroll
        for (int j = 0; j < 8; ++j) {
            float fq = bs2f((u16)aq[j]);
            float fk = bs2f((u16)ak[j]);
            sq += fq * fq;
            sk += fk * fk;
        }
    }
    sq += __shfl_xor(sq, 16); sq += __shfl_xor(sq, 32);
    sk += __shfl_xor(sk, 16); sk += __shfl_xor(sk, 32);
    if (q == 0) {
        atomicAdd(&qss[b * 64 + h * 16 + m], sq);
        atomicAdd(&kss[b * 64 + h * 16 + m], sk);
    }
    #pragma unroll
    for (int r = 0; r < 4; ++r) {
        int c = q * 4 + r;   // row of D
        atomicAdd(&gram[b * 1024 + h * 256 + c * 16 + m], acc[r]);
    }
}

// =================== softmax(cos-sim * temp) ===================
__global__ void attn_kernel(const float* __restrict__ gram, const float* __restrict__ qss,
                            const float* __restrict__ kss, const float* __restrict__ temp,
                            float* __restrict__ attn) {
    int bh = blockIdx.x;
    int b = bh >> 2, h = bh & 3;
    int tid = threadIdx.x;
    __shared__ float L[16][17];
    __shared__ float rowmax[16], rowsum[16];
    int c = tid >> 4, d = tid & 15;
    float qn = fmaxf(sqrtf(qss[b * 64 + h * 16 + c]), 1e-12f);
    float kn = fmaxf(sqrtf(kss[b * 64 + h * 16 + d]), 1e-12f);
    float lg = gram[b * 1024 + h * 256 + c * 16 + d] / (qn * kn) * temp[h];
    L[c][d] = lg;
    __syncthreads();
    if (tid < 16) {
        float m = -1e30f;
        for (int j = 0; j < 16; ++j) m = fmaxf(m, L[tid][j]);
        rowmax[tid] = m;
    }
    __syncthreads();
    float e = expf(lg - rowmax[c]);
    L[c][d] = e;
    __syncthreads();
    if (tid < 16) {
        float s = 0.f;
        for (int j = 0; j < 16; ++j) s += L[tid][j];
        rowsum[tid] = s;
    }
    __syncthreads();
    attn[b * 1024 + h * 256 + c * 16 + d] = e / rowsum[c];
}

// =================== fold v2 ===================
__global__ __launch_bounds__(256) void fold_v2(
        const float* __restrict__ attn, const float* __restrict__ w3,
        const float* __restrict__ b3, const float* __restrict__ wproj,
        short* __restrict__ WfoldF, float* __restrict__ bfold) {
    __shared__ float attn_s[1024];
    __shared__ float wp_s[64][65];
    __shared__ float Aeff_s[64][17];
    __shared__ float beff[64];
    int bt = blockIdx.y;
    int b = bt >> 2, t = bt & 3;
    int ci0 = blockIdx.x * 16;
    int tid = threadIdx.x;
    for (int i = 0; i < 4; ++i) attn_s[tid + i * 256] = attn[b * 1024 + tid + i * 256];
    #pragma unroll
    for (int i = 0; i < 16; ++i) {
        int idx = tid + i * 256;
        int co = idx >> 6, C = idx & 63;
        wp_s[co][C] = wproj[co * 128 + C];
    }
    __syncthreads();
    #pragma unroll
    for (int pass = 0; pass < 4; ++pass) {
        int el = pass * 256 + tid;
        int C = el >> 4, ci_l = el & 15;
        int h = C >> 4, c = C & 15;
        float s = 0.f;
        #pragma unroll
        for (int d = 0; d < 16; ++d)
            s += attn_s[h * 256 + c * 16 + d] * w3[(size_t)(4 * (h * 16 + d) + t) * 256 + ci0 + ci_l];
        Aeff_s[C][ci_l] = s;
    }
    if (blockIdx.x == 0 && tid < 64) {
        int h = tid >> 4, c = tid & 15;
        float s = 0.f;
        #pragma unroll
        for (int d = 0; d < 16; ++d)
            s += attn_s[h * 256 + c * 16 + d] * b3[4 * (h * 16 + d) + t];
        beff[tid] = s;
    }
    __syncthreads();
    #pragma unroll
    for (int pass = 0; pass < 4; ++pass) {
        int el = pass * 256 + tid;
        int ci_l = el >> 6, co = el & 63;
        float s = 0.f;
        #pragma unroll
        for (int C = 0; C < 64; ++C) s += wp_s[co][C] * Aeff_s[C][ci_l];
        int ci = ci0 + ci_l;
        int chk = ci >> 5;
        int s5 = ci & 31;
        int j = s5 & 7;
        int lane2 = (((s5 >> 3) << 4)) | (co & 15);
        int mt = co >> 4;
        WfoldF[(((size_t)(bt * 8 + chk) * 4 + mt)) * 512 + lane2 * 8 + j] = (short)f2bs(s);
    }
    if (blockIdx.x == 0 && tid < 64) {
        float s = 0.f;
        #pragma unroll
        for (int C = 0; C < 64; ++C) s += wp_s[tid][C] * beff[C];
        bfold[bt * 64 + tid] = s;
    }
}

// =================== final: out = Wfold[b,t]·D1 + bfold + Wp2·I2, fp32 out ===================
__global__ __launch_bounds__(256) void final_mfma(
        const short* __restrict__ D1, const short* __restrict__ I2,
        const short* __restrict__ WfoldF, const short* __restrict__ wpF,
        const float* __restrict__ bfold, float* __restrict__ out) {
    __shared__ short inS[8192];
    int tid = threadIdx.x;
    int lane = tid & 63, wv = tid >> 6;
    int q = lane >> 4, pl = lane & 15;
    int n0 = blockIdx.x * 256;
    int b = blockIdx.y;
    int t = n0 >> 14, m0 = n0 & 16383, bt = b * 4 + t;
    int px0w = wv * 64;
    f32x4 acc[4][4];
    #pragma unroll
    for (int mt = 0; mt < 4; ++mt) {
        float4 bf4 = *(const float4*)(bfold + bt * 64 + mt * 16 + q * 4);
        #pragma unroll
        for (int nt = 0; nt < 4; ++nt)
            acc[mt][nt] = (f32x4){bf4.x, bf4.y, bf4.z, bf4.w};
    }
    for (int ch = 0; ch < 8; ++ch) {
        if (ch) __syncthreads();
        const short* src = D1 + ((size_t)(b * 16384 + m0)) * 256 + ch * 32;
        for (int tt = tid; tt < 1024; tt += 256) {
            int pix = tt >> 2, hf = tt & 3;
            *(uint4*)(inS + pix * 32 + hf * 8) = *(const uint4*)(src + (size_t)pix * 256 + hf * 8);
        }
        short8 af[4];
        #pragma unroll
        for (int mt = 0; mt < 4; ++mt)
            af[mt] = *(const short8*)(WfoldF + ((size_t)(bt * 8 + ch)) * 2048 + mt * 512 + lane * 8);
        __syncthreads();
        #pragma unroll
        for (int nt = 0; nt < 4; ++nt) {
            short8 bfr = *(const short8*)(inS + (px0w + nt * 16 + pl) * 32 + q * 8);
            #pragma unroll
            for (int mt = 0; mt < 4; ++mt)
                acc[mt][nt] = __builtin_amdgcn_mfma_f32_16x16x32_bf16(af[mt], bfr, acc[mt][nt], 0, 0, 0);
        }
    }
    for (int ch = 0; ch < 2; ++ch) {
        __syncthreads();
        const short* src = I2 + ((size_t)(b * 65536 + n0)) * 64 + ch * 32;
        for (int tt = tid; tt < 1024; tt += 256) {
            int pix = tt >> 2, hf = tt & 3;
            *(uint4*)(inS + pix * 32 + hf * 8) = *(const uint4*)(src + (size_t)pix * 64 + hf * 8);
        }
        short8 af[4];
        #pragma unroll
        for (int mt = 0; mt < 4; ++mt)
            af[mt] = *(const short8*)(wpF + (size_t)ch * 2048 + mt * 512 + lane * 8);
        __syncthreads();
        #pragma unroll
        for (int nt = 0; nt < 4; ++nt) {
            short8 bfr = *(const short8*)(inS + (px0w + nt * 16 + pl) * 32 + q * 8);
            #pragma unroll
            for (int mt = 0; mt < 4; ++mt)
                acc[mt][nt] = __builtin_amdgcn_mfma_f32_16x16x32_bf16(af[mt], bfr, acc[mt][nt], 0, 0, 0);
        }
    }
    #pragma unroll
    for (int mt = 0; mt < 4; ++mt) {
        #pragma unroll
        for (int nt = 0; nt < 4; ++nt) {
            int n = n0 + px0w + nt * 16 + pl;
            #pragma unroll
            for (int r = 0; r < 4; ++r) {
                int co = mt * 16 + q * 4 + r;
                out[((size_t)(b * 64 + co)) * 65536 + n] = acc[mt][nt][r];
            }
        }
    }
}

extern "C" void kernel_launch(void* const* d_in, const int* in_sizes, int n_in,
                              void* d_out, int out_size, void* d_ws, size_t ws_size,
                              hipStream_t stream) {
    const float* x     = (const float*)d_in[0];
    const float* temp  = (const float*)d_in[1];
    const float* w1    = (const float*)d_in[2];
    const float* b1    = (const float*)d_in[3];
    const float* w2    = (const float*)d_in[4];
    const float* b2    = (const float*)d_in[5];
    const float* w3    = (const float*)d_in[6];
    const float* b3    = (const float*)d_in[7];
    const float* wdwt  = (const float*)d_in[8];
    const float* bdwt  = (const float*)d_in[9];
    const float* widwt = (const float*)d_in[10];
    const float* bidwt = (const float*)d_in[11];
    const float* wproj = (const float*)d_in[12];
    float* out = (float*)d_out;

    char* W8 = (char*)d_ws;
    const size_t SLOT = 16777216;
    short* slotA = (short*)(W8);              // D0 -> I0
    short* slotB = (short*)(W8 + SLOT);       // D1
    short* slotC = (short*)(W8 + 2 * SLOT);   // Qb -> I2
    short* slotD = (short*)(W8 + 3 * SLOT);   // Kb
    char* P = W8 + 4 * SLOT;
    short* wF1    = (short*)P; P += 2 * 655360;
    short* wF2c   = (short*)P; P += 2 * 40960;
    short* wFk    = (short*)P; P += 2 * 65536;
    short* wpF    = (short*)P; P += 2 * 4096;
    short* wFq    = (short*)P; P += 2 * 4096;
    short* WfoldF = (short*)P; P += 2 * 131072;
    float* scr    = (float*)P;
    float* qss   = scr;
    float* kss   = scr + 128;
    float* gram  = scr + 256;
    float* attn  = scr + 2304;
    float* bfold = scr + 4352;

    prep_all<<<3009, 256, 0, stream>>>(wdwt, widwt, w2, wproj, w1,
                                       wF1, wF2c, wFk, wpF, wFq, scr);

    // fused DWT + Q conv (x read once): D0 -> slotA, Qb -> slotC
    dwtq_kernel<<<dim3(2, 128, 2), 256, 0, stream>>>(x, wFq, b1, slotA, slotC);

    // DWT-branch 3x3 conv — v11: per-wave register-dbuf weights, no weight DMA/LDS
    conv3_v11<<<dim3(64, 4, 2), 256, 0, stream>>>(slotA, wF1, bdwt, slotB);

    // K conv + gram (frees slotC after gram)
    kconv_mfma<<<dim3(4, 64, 2), 256, 0, stream>>>(slotB, wFk, b2, slotD);
    gram_mfma<<<dim3(128, 2), 256, 0, stream>>>(slotC, slotD, qss, kss, gram);

    // IDWT branch (slotA reused for I0, slotC reused for I2)
    idwt_kernel<<<8192, 256, 0, stream>>>(slotB, slotA);
    // idwt-branch 3x3 conv — v12: v11 structure, XCD row-banding (was 123MB FETCH)
    conv3_v12<<<dim3(128, 2, 2), 256, 0, stream>>>(slotA, wF2c, bidwt, slotC);

    // softmax -> fold
    attn_kernel<<<8, 256, 0, stream>>>(gram, qss, kss, temp, attn);
    fold_v2<<<dim3(16, 8), 256, 0, stream>>>(attn, w3, b3, wproj, WfoldF, bfold);

    // fused (attn·V + proj) + idwt-branch proj
    final_mfma<<<dim3(256, 2), 256, 0, stream>>>(slotB, slotC, WfoldF, wpF, bfold, out);
}

// Round 10
// 247.834 us; speedup vs baseline: 1.1926x; 1.0289x over previous
//
#include <hip/hip_runtime.h>
#include <hip/hip_bf16.h>

typedef __hip_bfloat16 bf16;
typedef __attribute__((ext_vector_type(8))) short short8;
typedef __attribute__((ext_vector_type(4))) float f32x4;
typedef unsigned short u16;
typedef unsigned int u32;

static __device__ __forceinline__ u16 f2bs(float f) {
    bf16 h = __float2bfloat16(f);
    return *reinterpret_cast<u16*>(&h);
}
static __device__ __forceinline__ float bs2f(u16 u) {
    union { float f; u32 i; } x; x.i = ((u32)u) << 16; return x.f;
}
static __device__ __forceinline__ uint4 pack8(const u16* p) {
    uint4 v;
    v.x = (u32)p[0] | ((u32)p[1] << 16);
    v.y = (u32)p[2] | ((u32)p[3] << 16);
    v.z = (u32)p[4] | ((u32)p[5] << 16);
    v.w = (u32)p[6] | ((u32)p[7] << 16);
    return v;
}
// async global->LDS DMA, 16B per lane. Per-lane GLOBAL address, wave-uniform LDS base.
static __device__ __forceinline__ void gl16(const short* g, short* l) {
    __builtin_amdgcn_global_load_lds(
        (const __attribute__((address_space(1))) u32*)(g),
        (__attribute__((address_space(3))) u32*)(l), 16, 0, 0);
}

// =================== weight prep ===================
// classic layout [ocblk][ch][pr][mt][lane][j] — for ocblk=1 (C=64) this is already
// phase-major: phase P=(ch*5+pr) at offset P*2048 shorts (used by conv3_v12)
__device__ __forceinline__ void prep3_body(const float* __restrict__ w, short* __restrict__ wF,
                                           int C, int idx) {
    int j = idx & 7;
    int lane = (idx >> 3) & 63;
    int mt = (idx >> 9) & 3;
    int rest = idx >> 11;
    int pair = rest % 5;
    int bo = rest / 5;
    int nchunks = C / 16;
    int ch = bo % nchunks;
    int ocblk = bo / nchunks;
    int s = ((lane >> 4) * 8 + j);
    int tp = 2 * pair + (s >> 4);
    int ci = ch * 16 + (s & 15);
    int oc = ocblk * 64 + mt * 16 + (lane & 15);
    float v = (tp <= 8) ? w[((size_t)(oc * C + ci)) * 9 + tp] : 0.f;
    wF[idx] = (short)f2bs(v);
}
// phase-major layout [ch][pr][ocg][mt][lane][j] for conv3_v11 (4KB per (phase,ocg))
__device__ __forceinline__ void prep3_chpr(const float* __restrict__ w, short* __restrict__ wF,
                                           int idx) {
    int j = idx & 7;
    int lane = (idx >> 3) & 63;
    int mt = (idx >> 9) & 3;
    int rest = idx >> 11;
    int ocg = rest & 3;
    int r2 = rest >> 2;
    int pr = r2 % 5;
    int ch = r2 / 5;
    int s = ((lane >> 4) * 8 + j);
    int tp = 2 * pr + (s >> 4);
    int ci = ch * 16 + (s & 15);
    int oc = ocg * 64 + mt * 16 + (lane & 15);
    float v = (tp <= 8) ? w[((size_t)(oc * 256 + ci)) * 9 + tp] : 0.f;
    wF[idx] = (short)f2bs(v);
}
__device__ __forceinline__ void prep1_body(const float* __restrict__ w, short* __restrict__ wF,
                                           int Cin, int cioff, int nchunks, int idx) {
    int j = idx & 7;
    int lane = (idx >> 3) & 63;
    int mt = (idx >> 9) & 3;
    int bo = idx >> 11;
    int ch = bo % nchunks;
    int ocblk = bo / nchunks;
    int s = (lane >> 4) * 8 + j;
    int ci = cioff + ch * 32 + s;
    int oc = ocblk * 64 + mt * 16 + (lane & 15);
    wF[idx] = (short)f2bs(w[(size_t)oc * Cin + ci]);
}

__global__ __launch_bounds__(256) void prep_all(
        const float* __restrict__ wdwt, const float* __restrict__ widwt,
        const float* __restrict__ w2, const float* __restrict__ wproj,
        const float* __restrict__ w1,
        short* __restrict__ wF1, short* __restrict__ wF2c, short* __restrict__ wFk,
        short* __restrict__ wpF, short* __restrict__ wFq, float* __restrict__ scr) {
    int blk = blockIdx.x;
    int tid = threadIdx.x;
    if (blk < 2560) {
        prep3_chpr(wdwt, wF1, blk * 256 + tid);
    } else if (blk < 2720) {
        prep3_body(widwt, wF2c, 64, (blk - 2560) * 256 + tid);
    } else if (blk < 2976) {
        prep1_body(w2, wFk, 256, 0, 8, (blk - 2720) * 256 + tid);
    } else if (blk < 2992) {
        prep1_body(wproj, wpF, 128, 64, 2, (blk - 2976) * 256 + tid);
    } else if (blk < 3008) {
        prep1_body(w1, wFq, 64, 0, 2, (blk - 2992) * 256 + tid);
    } else {
        for (int i = tid; i < 4864; i += 256) scr[i] = 0.f;
    }
}

// =================== fused Haar DWT + Q conv ===================
__global__ __launch_bounds__(256) void dwtq_kernel(
        const float* __restrict__ x, const short* __restrict__ wFq,
        const float* __restrict__ b1, short* __restrict__ d0, short* __restrict__ outQ) {
    __shared__ short ls[256 * 72];
    int tid = threadIdx.x;
    int lane = tid & 63, wv = tid >> 6;
    int q = lane >> 4, pl = lane & 15;
    int xh = blockIdx.x;
    int y2 = blockIdx.y;
    int b = blockIdx.z;
    int x0 = xh * 128;

    #pragma unroll
    for (int k2 = 0; k2 < 16; ++k2) {
        int u = k2 * 256 + tid;
        int ch = u & 63;
        int xu = (u >> 6) & 31;
        int r = (u >> 11) & 1;
        float4 v = *(const float4*)(x + (((size_t)(b * 64 + ch) * 256 + (2 * y2 + r))) * 256 + x0 + xu * 4);
        ls[(r * 128 + xu * 4 + 0) * 72 + ch] = (short)f2bs(v.x);
        ls[(r * 128 + xu * 4 + 1) * 72 + ch] = (short)f2bs(v.y);
        ls[(r * 128 + xu * 4 + 2) * 72 + ch] = (short)f2bs(v.z);
        ls[(r * 128 + xu * 4 + 3) * 72 + ch] = (short)f2bs(v.w);
    }
    __syncthreads();

    f32x4 acc[4][4];
    #pragma unroll
    for (int mt = 0; mt < 4; ++mt)
        #pragma unroll
        for (int nt = 0; nt < 4; ++nt)
            acc[mt][nt] = (f32x4){0.f, 0.f, 0.f, 0.f};
    #pragma unroll
    for (int chk = 0; chk < 2; ++chk) {
        short8 af[4];
        #pragma unroll
        for (int mt = 0; mt < 4; ++mt)
            af[mt] = *(const short8*)(wFq + (chk * 4 + mt) * 512 + lane * 8);
        #pragma unroll
        for (int nt = 0; nt < 4; ++nt) {
            int p = wv * 64 + nt * 16 + pl;
            short8 bfr = *(const short8*)(ls + p * 72 + chk * 32 + q * 8);
            #pragma unroll
            for (int mt = 0; mt < 4; ++mt)
                acc[mt][nt] = __builtin_amdgcn_mfma_f32_16x16x32_bf16(af[mt], bfr, acc[mt][nt], 0, 0, 0);
        }
    }
    #pragma unroll
    for (int mt = 0; mt < 4; ++mt) {
        int ocb = mt * 16 + q * 4;
        float4 bi = *(const float4*)(b1 + ocb);
        float bia[4] = {bi.x, bi.y, bi.z, bi.w};
        #pragma unroll
        for (int nt = 0; nt < 4; ++nt) {
            int p = wv * 64 + nt * 16 + pl;
            int n = (2 * y2 + (p >> 7)) * 256 + x0 + (p & 127);
            #pragma unroll
            for (int r = 0; r < 4; ++r)
                outQ[((size_t)(b * 64 + ocb + r)) * 65536 + n] = (short)f2bs(acc[mt][nt][r] + bia[r]);
        }
    }

    int xl = tid >> 2;
    int cg = tid & 3;
    int c0 = cg * 16;
    u16 obuf[4][16];
    #pragma unroll
    for (int cl = 0; cl < 16; ++cl) {
        int c = c0 + cl;
        float a  = bs2f(ls[(2 * xl) * 72 + c]);
        float bb = bs2f(ls[(2 * xl + 1) * 72 + c]);
        float c2 = bs2f(ls[(128 + 2 * xl) * 72 + c]);
        float dd = bs2f(ls[(128 + 2 * xl + 1) * 72 + c]);
        obuf[0][cl] = f2bs((a - bb + c2 - dd) * 0.5f);  // lh
        obuf[1][cl] = f2bs((a + bb - c2 - dd) * 0.5f);  // hl
        obuf[2][cl] = f2bs((a - bb - c2 + dd) * 0.5f);  // hh
        obuf[3][cl] = f2bs((a + bb + c2 + dd) * 0.5f);  // ll
    }
    int xd = xh * 64 + xl;
    size_t P = ((size_t)(b * 128 + y2) * 128 + xd) * 256;
    #pragma unroll
    for (int g = 0; g < 4; ++g) {
        *(uint4*)&d0[P + g * 64 + c0]     = pack8(&obuf[g][0]);
        *(uint4*)&d0[P + g * 64 + c0 + 8] = pack8(&obuf[g][8]);
    }
}

// =================== Haar IDWT ===================
__global__ __launch_bounds__(256) void idwt_kernel(const short* __restrict__ d1, short* __restrict__ i0) {
    int tid = threadIdx.x;
    int lane = tid & 63;
    int p = blockIdx.x * 4 + (tid >> 6);
    int b = p >> 14, m = p & 16383;
    ushort4 v = *(const ushort4*)(d1 + ((size_t)(b * 16384 + m)) * 256 + 4 * lane);
    float yl = bs2f(v.x), lh = bs2f(v.y), hl = bs2f(v.z), hh = bs2f(v.w);
    float a_ = (yl + lh + hl + hh) * 0.5f;
    float b_ = (yl - lh + hl - hh) * 0.5f;
    float c_ = (yl + lh - hl - hh) * 0.5f;
    float d_ = (yl - lh - hl + hh) * 0.5f;
    int y = m >> 7, xx = m & 127;
    u16* o = (u16*)i0;
    size_t base = ((size_t)(b * 256 + 2 * y) * 256 + 2 * xx) * 64 + lane;
    o[base] = f2bs(a_);
    o[base + 64] = f2bs(b_);
    o[base + 256 * 64] = f2bs(c_);
    o[base + 256 * 64 + 64] = f2bs(d_);
}

// =================== 3x3 conv v13 (C=256, H=W=128): v11 minus intra-chunk barriers ===
// v11's per-phase __syncthreads was a vestige of the LDS-weight versions. Weights are
// per-wave registers and ibuf[ch&1] is stable for all 5 phases of a chunk, so there
// are NO cross-wave hazards inside a chunk. One barrier per chunk suffices:
//  - DMA(ch+1) writes ibuf[(ch+1)&1], last read in chunk ch-1 which ended with a
//    barrier before the DMA issues -> safe.
//  - chunk ch+1's reads need DMA drained: the chunk-ch end barrier's implicit
//    vmcnt(0) handles it.
// 80 barriers -> 16: waves slip within a chunk, weight-load latency and ds_reads
// overlap MFMA across the whole 5-phase window instead of re-convoying every phase.
#define PHASE_NB11(P, WC, WN)                                                     \
    {                                                                             \
        const int P_ = (P);                                                       \
        const int ch_ = P_ / 5;                                                   \
        const int pr_ = P_ - ch_ * 5;                                             \
        if (P_ + 1 < 80) {                                                        \
            const short* wn = wF + ((size_t)((P_ + 1) * 4 + ocg)) * 2048;         \
            _Pragma("unroll")                                                     \
            for (int mt = 0; mt < 4; ++mt)                                        \
                WN[mt] = *(const short8*)(wn + mt * 512 + lane * 8);              \
        }                                                                         \
        if (pr_ == 0 && ch_ < 15) {                                               \
            short* id = ibuf[(ch_ + 1) & 1];                                      \
            _Pragma("unroll")                                                     \
            for (int k2 = 0; k2 < UPT; ++k2)                                      \
                if (act[k2]) gl16(gp[k2] + (ch_ + 1) * 16, id + ibo[k2]);         \
        }                                                                         \
        const short* ib = ibuf[ch_ & 1];                                          \
        int t1 = 2 * pr_ + (q >> 1);                                              \
        if (t1 > 8) t1 = 8;                                                       \
        int ti = (t1 >= 6) ? 2 : ((t1 >= 3) ? 1 : 0);                             \
        int tj = t1 - ti * 3;                                                     \
        _Pragma("unroll")                                                         \
        for (int nt = 0; nt < 4; ++nt) {                                          \
            int i = colbase + nt * 16 + pl + tj;                                  \
            short8 bfr = *(const short8*)(ib + ((ti + orow) * Wp + i) * 16 + (q & 1) * 8); \
            _Pragma("unroll")                                                     \
            for (int mt = 0; mt < 4; ++mt)                                        \
                acc[mt][nt] = __builtin_amdgcn_mfma_f32_16x16x32_bf16(WC[mt], bfr, acc[mt][nt], 0, 0, 0); \
        }                                                                         \
    }

__global__ __launch_bounds__(256) void conv3_v13(
        const short* __restrict__ in, const short* __restrict__ wF,
        const float* __restrict__ bias, short* __restrict__ out) {
    constexpr int C = 256, W = 128, H = 128;
    constexpr int Wp = W + 2;              // 130 staged cols
    constexpr int UNITS = 4 * Wp * 2;      // 1040 16B-units per input chunk (4 rows)
    constexpr int UPT = 5;                 // ceil(1040/256)
    __shared__ short ibuf[2][4 * Wp * 16]; // 2 x 16.64 KB (input only; weights in regs)

    int tid = threadIdx.x;
    int lane = tid & 63, wv = tid >> 6;
    int q = lane >> 4, pl = lane & 15;
    int ocg = blockIdx.y;
    int bx = blockIdx.x;                   // row-pair index 0..63
    int rp = ((bx & 7) << 3) | (bx >> 3);  // bijective 8x8: XCD k owns row-pairs [8k,8k+8)
    int y0 = rp * 2;
    int b = blockIdx.z;
    int orow = wv >> 1;                    // which of the 2 output rows
    int colbase = (wv & 1) * 64;           // which 64-px half

    const short* gp[UPT];
    int ibo[UPT];
    bool act[UPT];
    #pragma unroll
    for (int k2 = 0; k2 < UPT; ++k2) {
        int u = k2 * 256 + tid;
        act[k2] = (u < UNITS);
        int uu = act[k2] ? u : 0;
        int r = uu / (Wp * 2);
        int rem = uu - r * (Wp * 2);
        int px = rem >> 1, hf = rem & 1;
        int ry = y0 - 1 + r;
        if (ry < 0) ry = 1;
        if (ry >= H) ry = 2 * H - 2 - ry;
        int rx = px - 1;
        if (rx < 0) rx = 1;
        if (rx >= W) rx = W - 2;
        gp[k2] = in + ((b * H + ry) * W + rx) * C + hf * 8;
        ibo[k2] = (k2 * 256 + wv * 64) * 8;   // wave-uniform LDS base (lane*16B auto)
    }

    f32x4 acc[4][4];
    #pragma unroll
    for (int mt = 0; mt < 4; ++mt)
        #pragma unroll
        for (int nt = 0; nt < 4; ++nt)
            acc[mt][nt] = (f32x4){0.f, 0.f, 0.f, 0.f};

    short8 wA[4], wB[4];
    {
        const short* w0 = wF + ((size_t)(0 * 4 + ocg)) * 2048;
        #pragma unroll
        for (int mt = 0; mt < 4; ++mt)
            wA[mt] = *(const short8*)(w0 + mt * 512 + lane * 8);
    }
    #pragma unroll
    for (int k2 = 0; k2 < UPT; ++k2)
        if (act[k2]) gl16(gp[k2], &ibuf[0][ibo[k2]]);
    __syncthreads();

    #pragma unroll 1
    for (int cp = 0; cp < 8; ++cp) {
        int base = cp * 10;
        // chunk 2cp (phases base+0..base+4), then one barrier
        PHASE_NB11(base + 0, wA, wB)
        PHASE_NB11(base + 1, wB, wA)
        PHASE_NB11(base + 2, wA, wB)
        PHASE_NB11(base + 3, wB, wA)
        PHASE_NB11(base + 4, wA, wB)
        __syncthreads();
        // chunk 2cp+1 (phases base+5..base+9), then one barrier
        PHASE_NB11(base + 5, wB, wA)
        PHASE_NB11(base + 6, wA, wB)
        PHASE_NB11(base + 7, wB, wA)
        PHASE_NB11(base + 8, wA, wB)
        PHASE_NB11(base + 9, wB, wA)
        __syncthreads();
    }

    int yout = y0 + orow;
    #pragma unroll
    for (int mt = 0; mt < 4; ++mt) {
        int ocb = ocg * 64 + mt * 16 + q * 4;
        float4 bi = *(const float4*)(bias + ocb);
        float bia[4] = {bi.x, bi.y, bi.z, bi.w};
        #pragma unroll
        for (int nt = 0; nt < 4; ++nt) {
            int xl = colbase + nt * 16 + pl;
            ushort4 pk;
            float v0 = acc[mt][nt][0] + bia[0]; pk.x = f2bs(v0 >= 0.f ? v0 : 0.01f * v0);
            float v1 = acc[mt][nt][1] + bia[1]; pk.y = f2bs(v1 >= 0.f ? v1 : 0.01f * v1);
            float v2 = acc[mt][nt][2] + bia[2]; pk.z = f2bs(v2 >= 0.f ? v2 : 0.01f * v2);
            float v3 = acc[mt][nt][3] + bia[3]; pk.w = f2bs(v3 >= 0.f ? v3 : 0.01f * v3);
            *(ushort4*)(out + (((size_t)(b * H + yout)) * W + xl) * C + ocb) = pk;
        }
    }
}

// =================== 3x3 conv v14 (C=64, H=W=256): v12 minus intra-chunk barriers ===
#define PHASE_NB12(P, WC, WN)                                                     \
    {                                                                             \
        const int P_ = (P);                                                       \
        const int ch_ = P_ / 5;                                                   \
        const int pr_ = P_ - ch_ * 5;                                             \
        if (P_ + 1 < 20) {                                                        \
            const short* wn = wF + ((size_t)(P_ + 1)) * 2048;                     \
            _Pragma("unroll")                                                     \
            for (int mt = 0; mt < 4; ++mt)                                        \
                WN[mt] = *(const short8*)(wn + mt * 512 + lane * 8);              \
        }                                                                         \
        if (pr_ == 0 && ch_ < 3) {                                                \
            short* id = ibuf[(ch_ + 1) & 1];                                      \
            _Pragma("unroll")                                                     \
            for (int k2 = 0; k2 < UPT; ++k2)                                      \
                if (act[k2]) gl16(gp[k2] + (ch_ + 1) * 16, id + ibo[k2]);         \
        }                                                                         \
        const short* ib = ibuf[ch_ & 1];                                          \
        int t1 = 2 * pr_ + (q >> 1);                                              \
        if (t1 > 8) t1 = 8;                                                       \
        int ti = (t1 >= 6) ? 2 : ((t1 >= 3) ? 1 : 0);                             \
        int tj = t1 - ti * 3;                                                     \
        _Pragma("unroll")                                                         \
        for (int nt = 0; nt < 4; ++nt) {                                          \
            int i = colbase + nt * 16 + pl + tj;                                  \
            short8 bfr = *(const short8*)(ib + ((ti + orow) * Wp + i) * 16 + (q & 1) * 8); \
            _Pragma("unroll")                                                     \
            for (int mt = 0; mt < 4; ++mt)                                        \
                acc[mt][nt] = __builtin_amdgcn_mfma_f32_16x16x32_bf16(WC[mt], bfr, acc[mt][nt], 0, 0, 0); \
        }                                                                         \
    }

__global__ __launch_bounds__(256) void conv3_v14(
        const short* __restrict__ in, const short* __restrict__ wF,
        const float* __restrict__ bias, short* __restrict__ out) {
    constexpr int C = 64, W = 256, H = 256;
    constexpr int Wp = 130;                // 128-col window + halo
    constexpr int UNITS = 4 * Wp * 2;      // 1040 16B-units per input chunk (4 rows)
    constexpr int UPT = 5;                 // ceil(1040/256)
    __shared__ short ibuf[2][4 * Wp * 16]; // 2 x 16.64 KB

    int tid = threadIdx.x;
    int lane = tid & 63, wv = tid >> 6;
    int q = lane >> 4, pl = lane & 15;
    int bx = blockIdx.x;                   // row-pair index 0..127
    int rp = ((bx & 7) << 4) | (bx >> 3);  // XCD k owns row-pairs [16k,16k+16)
    int y0 = rp * 2;
    int xh = blockIdx.y;
    int x0 = xh * 128;
    int b = blockIdx.z;
    int orow = wv >> 1;                    // which of the 2 output rows
    int colbase = (wv & 1) * 64;           // which 64-px half

    const short* gp[UPT];
    int ibo[UPT];
    bool act[UPT];
    #pragma unroll
    for (int k2 = 0; k2 < UPT; ++k2) {
        int u = k2 * 256 + tid;
        act[k2] = (u < UNITS);
        int uu = act[k2] ? u : 0;
        int r = uu / (Wp * 2);
        int rem = uu - r * (Wp * 2);
        int px = rem >> 1, hf = rem & 1;
        int ry = y0 - 1 + r;
        if (ry < 0) ry = 1;
        if (ry >= H) ry = 2 * H - 2 - ry;
        int rx = x0 - 1 + px;
        if (rx < 0) rx = 1;
        if (rx >= W) rx = 2 * W - 2 - rx;
        gp[k2] = in + ((b * H + ry) * W + rx) * C + hf * 8;
        ibo[k2] = (k2 * 256 + wv * 64) * 8;   // wave-uniform LDS base (lane*16B auto)
    }

    f32x4 acc[4][4];
    #pragma unroll
    for (int mt = 0; mt < 4; ++mt)
        #pragma unroll
        for (int nt = 0; nt < 4; ++nt)
            acc[mt][nt] = (f32x4){0.f, 0.f, 0.f, 0.f};

    short8 wA[4], wB[4];
    {
        #pragma unroll
        for (int mt = 0; mt < 4; ++mt)
            wA[mt] = *(const short8*)(wF + mt * 512 + lane * 8);
    }
    #pragma unroll
    for (int k2 = 0; k2 < UPT; ++k2)
        if (act[k2]) gl16(gp[k2], &ibuf[0][ibo[k2]]);
    __syncthreads();

    #pragma unroll 1
    for (int cp = 0; cp < 2; ++cp) {
        int base = cp * 10;
        PHASE_NB12(base + 0, wA, wB)
        PHASE_NB12(base + 1, wB, wA)
        PHASE_NB12(base + 2, wA, wB)
        PHASE_NB12(base + 3, wB, wA)
        PHASE_NB12(base + 4, wA, wB)
        __syncthreads();
        PHASE_NB12(base + 5, wB, wA)
        PHASE_NB12(base + 6, wA, wB)
        PHASE_NB12(base + 7, wB, wA)
        PHASE_NB12(base + 8, wA, wB)
        PHASE_NB12(base + 9, wB, wA)
        __syncthreads();
    }

    int yout = y0 + orow;
    #pragma unroll
    for (int mt = 0; mt < 4; ++mt) {
        int ocb = mt * 16 + q * 4;
        float4 bi = *(const float4*)(bias + ocb);
        float bia[4] = {bi.x, bi.y, bi.z, bi.w};
        #pragma unroll
        for (int nt = 0; nt < 4; ++nt) {
            int xl = x0 + colbase + nt * 16 + pl;
            ushort4 pk;
            float v0 = acc[mt][nt][0] + bia[0]; pk.x = f2bs(v0 >= 0.f ? v0 : 0.01f * v0);
            float v1 = acc[mt][nt][1] + bia[1]; pk.y = f2bs(v1 >= 0.f ? v1 : 0.01f * v1);
            float v2 = acc[mt][nt][2] + bia[2]; pk.z = f2bs(v2 >= 0.f ? v2 : 0.01f * v2);
            float v3 = acc[mt][nt][3] + bia[3]; pk.w = f2bs(v3 >= 0.f ? v3 : 0.01f * v3);
            *(ushort4*)(out + (((size_t)(b * H + yout)) * W + xl) * C + ocb) = pk;
        }
    }
}

// =================== K conv 1x1 MFMA ===================
__global__ __launch_bounds__(256) void kconv_mfma(
        const short* __restrict__ in, const short* __restrict__ wF,
        const float* __restrict__ bias, short* __restrict__ outK) {
    __shared__ short inS[8192];
    int tid = threadIdx.x;
    int lane = tid & 63, wv = tid >> 6;
    int q = lane >> 4, pl = lane & 15;
    int ocblk = blockIdx.x;
    int m0 = blockIdx.y * 256;
    int b = blockIdx.z;
    int px0w = wv * 64;
    f32x4 acc[4][4];
    #pragma unroll
    for (int mt = 0; mt < 4; ++mt)
        #pragma unroll
        for (int nt = 0; nt < 4; ++nt)
            acc[mt][nt] = (f32x4){0.f, 0.f, 0.f, 0.f};

    for (int ch = 0; ch < 8; ++ch) {
        if (ch) __syncthreads();
        const short* src = in + ((size_t)(b * 16384 + m0)) * 256 + ch * 32;
        for (int t = tid; t < 1024; t += 256) {
            int pix = t >> 2, hf = t & 3;
            *(uint4*)(inS + pix * 32 + hf * 8) = *(const uint4*)(src + (size_t)pix * 256 + hf * 8);
        }
        short8 af[4];
        #pragma unroll
        for (int mt = 0; mt < 4; ++mt)
            af[mt] = *(const short8*)(wF + ((size_t)(ocblk * 8 + ch)) * 2048 + mt * 512 + lane * 8);
        __syncthreads();
        #pragma unroll
        for (int nt = 0; nt < 4; ++nt) {
            short8 bfr = *(const short8*)(inS + (px0w + nt * 16 + pl) * 32 + q * 8);
            #pragma unroll
            for (int mt = 0; mt < 4; ++mt)
                acc[mt][nt] = __builtin_amdgcn_mfma_f32_16x16x32_bf16(af[mt], bfr, acc[mt][nt], 0, 0, 0);
        }
    }
    #pragma unroll
    for (int mt = 0; mt < 4; ++mt) {
        int ocb = ocblk * 64 + mt * 16 + q * 4;
        float4 bi = *(const float4*)(bias + ocb);
        float bia[4] = {bi.x, bi.y, bi.z, bi.w};
        #pragma unroll
        for (int nt = 0; nt < 4; ++nt) {
            int n = m0 + px0w + nt * 16 + pl;
            #pragma unroll
            for (int r = 0; r < 4; ++r) {
                int co = ocb + r;
                outK[((size_t)(b * 64 + (co >> 2))) * 65536 + (co & 3) * 16384 + n] =
                    (short)f2bs(acc[mt][nt][r] + bia[r]);
            }
        }
    }
}

// =================== Gram via MFMA: per-head 16x16 Q.K^T + row norms ===================
__global__ __launch_bounds__(256) void gram_mfma(
        const short* __restrict__ Q, const short* __restrict__ K,
        float* __restrict__ qss, float* __restrict__ kss, float* __restrict__ gram) {
    int tid = threadIdx.x;
    int lane = tid & 63, h = tid >> 6;
    int q = lane >> 4, m = lane & 15;
    int b = blockIdx.y;
    int n0 = blockIdx.x * 512;
    const short* qrow = Q + ((size_t)(b * 64 + h * 16 + m)) * 65536 + n0 + q * 8;
    const short* krow = K + ((size_t)(b * 64 + h * 16 + m)) * 65536 + n0 + q * 8;
    f32x4 acc = (f32x4){0.f, 0.f, 0.f, 0.f};
    float sq = 0.f, sk = 0.f;
    #pragma unroll 4
    for (int it = 0; it < 16; ++it) {
        short8 aq = *(const short8*)(qrow + it * 32);
        short8 ak = *(const short8*)(krow + it * 32);
        acc = __builtin_amdgcn_mfma_f32_16x16x32_bf16(aq, ak, acc, 0, 0, 0);
        #pragma unroll
        for (int j = 0; j < 8; ++j) {
            float fq = bs2f((u16)aq[j]);
            float fk = bs2f((u16)ak[j]);
            sq += fq * fq;
            sk += fk * fk;
        }
    }
    sq += __shfl_xor(sq, 16); sq += __shfl_xor(sq, 32);
    sk += __shfl_xor(sk, 16); sk += __shfl_xor(sk, 32);
    if (q == 0) {
        atomicAdd(&qss[b * 64 + h * 16 + m], sq);
        atomicAdd(&kss[b * 64 + h * 16 + m], sk);
    }
    #pragma unroll
    for (int r = 0; r < 4; ++r) {
        int c = q * 4 + r;   // row of D
        atomicAdd(&gram[b * 1024 + h * 256 + c * 16 + m], acc[r]);
    }
}

// =================== softmax(cos-sim * temp) ===================
__global__ void attn_kernel(const float* __restrict__ gram, const float* __restrict__ qss,
                            const float* __restrict__ kss, const float* __restrict__ temp,
                            float* __restrict__ attn) {
    int bh = blockIdx.x;
    int b = bh >> 2, h = bh & 3;
    int tid = threadIdx.x;
    __shared__ float L[16][17];
    __shared__ float rowmax[16], rowsum[16];
    int c = tid >> 4, d = tid & 15;
    float qn = fmaxf(sqrtf(qss[b * 64 + h * 16 + c]), 1e-12f);
    float kn = fmaxf(sqrtf(kss[b * 64 + h * 16 + d]), 1e-12f);
    float lg = gram[b * 1024 + h * 256 + c * 16 + d] / (qn * kn) * temp[h];
    L[c][d] = lg;
    __syncthreads();
    if (tid < 16) {
        float m = -1e30f;
        for (int j = 0; j < 16; ++j) m = fmaxf(m, L[tid][j]);
        rowmax[tid] = m;
    }
    __syncthreads();
    float e = expf(lg - rowmax[c]);
    L[c][d] = e;
    __syncthreads();
    if (tid < 16) {
        float s = 0.f;
        for (int j = 0; j < 16; ++j) s += L[tid][j];
        rowsum[tid] = s;
    }
    __syncthreads();
    attn[b * 1024 + h * 256 + c * 16 + d] = e / rowsum[c];
}

// =================== fold v2 ===================
__global__ __launch_bounds__(256) void fold_v2(
        const float* __restrict__ attn, const float* __restrict__ w3,
        const float* __restrict__ b3, const float* __restrict__ wproj,
        short* __restrict__ WfoldF, float* __restrict__ bfold) {
    __shared__ float attn_s[1024];
    __shared__ float wp_s[64][65];
    __shared__ float Aeff_s[64][17];
    __shared__ float beff[64];
    int bt = blockIdx.y;
    int b = bt >> 2, t = bt & 3;
    int ci0 = blockIdx.x * 16;
    int tid = threadIdx.x;
    for (int i = 0; i < 4; ++i) attn_s[tid + i * 256] = attn[b * 1024 + tid + i * 256];
    #pragma unroll
    for (int i = 0; i < 16; ++i) {
        int idx = tid + i * 256;
        int co = idx >> 6, C = idx & 63;
        wp_s[co][C] = wproj[co * 128 + C];
    }
    __syncthreads();
    #pragma unroll
    for (int pass = 0; pass < 4; ++pass) {
        int el = pass * 256 + tid;
        int C = el >> 4, ci_l = el & 15;
        int h = C >> 4, c = C & 15;
        float s = 0.f;
        #pragma unroll
        for (int d = 0; d < 16; ++d)
            s += attn_s[h * 256 + c * 16 + d] * w3[(size_t)(4 * (h * 16 + d) + t) * 256 + ci0 + ci_l];
        Aeff_s[C][ci_l] = s;
    }
    if (blockIdx.x == 0 && tid < 64) {
        int h = tid >> 4, c = tid & 15;
        float s = 0.f;
        #pragma unroll
        for (int d = 0; d < 16; ++d)
            s += attn_s[h * 256 + c * 16 + d] * b3[4 * (h * 16 + d) + t];
        beff[tid] = s;
    }
    __syncthreads();
    #pragma unroll
    for (int pass = 0; pass < 4; ++pass) {
        int el = pass * 256 + tid;
        int ci_l = el >> 6, co = el & 63;
        float s = 0.f;
        #pragma unroll
        for (int C = 0; C < 64; ++C) s += wp_s[co][C] * Aeff_s[C][ci_l];
        int ci = ci0 + ci_l;
        int chk = ci >> 5;
        int s5 = ci & 31;
        int j = s5 & 7;
        int lane2 = (((s5 >> 3) << 4)) | (co & 15);
        int mt = co >> 4;
        WfoldF[(((size_t)(bt * 8 + chk) * 4 + mt)) * 512 + lane2 * 8 + j] = (short)f2bs(s);
    }
    if (blockIdx.x == 0 && tid < 64) {
        float s = 0.f;
        #pragma unroll
        for (int C = 0; C < 64; ++C) s += wp_s[tid][C] * beff[C];
        bfold[bt * 64 + tid] = s;
    }
}

// =================== final: out = Wfold[b,t]·D1 + bfold + Wp2·I2, fp32 out ===================
__global__ __launch_bounds__(256) void final_mfma(
        const short* __restrict__ D1, const short* __restrict__ I2,
        const short* __restrict__ WfoldF, const short* __restrict__ wpF,
        const float* __restrict__ bfold, float* __restrict__ out) {
    __shared__ short inS[8192];
    int tid = threadIdx.x;
    int lane = tid & 63, wv = tid >> 6;
    int q = lane >> 4, pl = lane & 15;
    int n0 = blockIdx.x * 256;
    int b = blockIdx.y;
    int t = n0 >> 14, m0 = n0 & 16383, bt = b * 4 + t;
    int px0w = wv * 64;
    f32x4 acc[4][4];
    #pragma unroll
    for (int mt = 0; mt < 4; ++mt) {
        float4 bf4 = *(const float4*)(bfold + bt * 64 + mt * 16 + q * 4);
        #pragma unroll
        for (int nt = 0; nt < 4; ++nt)
            acc[mt][nt] = (f32x4){bf4.x, bf4.y, bf4.z, bf4.w};
    }
    for (int ch = 0; ch < 8; ++ch) {
        if (ch) __syncthreads();
        const short* src = D1 + ((size_t)(b * 16384 + m0)) * 256 + ch * 32;
        for (int tt = tid; tt < 1024; tt += 256) {
            int pix = tt >> 2, hf = tt & 3;
            *(uint4*)(inS + pix * 32 + hf * 8) = *(const uint4*)(src + (size_t)pix * 256 + hf * 8);
        }
        short8 af[4];
        #pragma unroll
        for (int mt = 0; mt < 4; ++mt)
            af[mt] = *(const short8*)(WfoldF + ((size_t)(bt * 8 + ch)) * 2048 + mt * 512 + lane * 8);
        __syncthreads();
        #pragma unroll
        for (int nt = 0; nt < 4; ++nt) {
            short8 bfr = *(const short8*)(inS + (px0w + nt * 16 + pl) * 32 + q * 8);
            #pragma unroll
            for (int mt = 0; mt < 4; ++mt)
                acc[mt][nt] = __builtin_amdgcn_mfma_f32_16x16x32_bf16(af[mt], bfr, acc[mt][nt], 0, 0, 0);
        }
    }
    for (int ch = 0; ch < 2; ++ch) {
        __syncthreads();
        const short* src = I2 + ((size_t)(b * 65536 + n0)) * 64 + ch * 32;
        for (int tt = tid; tt < 1024; tt += 256) {
            int pix = tt >> 2, hf = tt & 3;
            *(uint4*)(inS + pix * 32 + hf * 8) = *(const uint4*)(src + (size_t)pix * 64 + hf * 8);
        }
        short8 af[4];
        #pragma unroll
        for (int mt = 0; mt < 4; ++mt)
            af[mt] = *(const short8*)(wpF + (size_t)ch * 2048 + mt * 512 + lane * 8);
        __syncthreads();
        #pragma unroll
        for (int nt = 0; nt < 4; ++nt) {
            short8 bfr = *(const short8*)(inS + (px0w + nt * 16 + pl) * 32 + q * 8);
            #pragma unroll
            for (int mt = 0; mt < 4; ++mt)
                acc[mt][nt] = __builtin_amdgcn_mfma_f32_16x16x32_bf16(af[mt], bfr, acc[mt][nt], 0, 0, 0);
        }
    }
    #pragma unroll
    for (int mt = 0; mt < 4; ++mt) {
        #pragma unroll
        for (int nt = 0; nt < 4; ++nt) {
            int n = n0 + px0w + nt * 16 + pl;
            #pragma unroll
            for (int r = 0; r < 4; ++r) {
                int co = mt * 16 + q * 4 + r;
                out[((size_t)(b * 64 + co)) * 65536 + n] = acc[mt][nt][r];
            }
        }
    }
}

extern "C" void kernel_launch(void* const* d_in, const int* in_sizes, int n_in,
                              void* d_out, int out_size, void* d_ws, size_t ws_size,
                              hipStream_t stream) {
    const float* x     = (const float*)d_in[0];
    const float* temp  = (const float*)d_in[1];
    const float* w1    = (const float*)d_in[2];
    const float* b1    = (const float*)d_in[3];
    const float* w2    = (const float*)d_in[4];
    const float* b2    = (const float*)d_in[5];
    const float* w3    = (const float*)d_in[6];
    const float* b3    = (const float*)d_in[7];
    const float* wdwt  = (const float*)d_in[8];
    const float* bdwt  = (const float*)d_in[9];
    const float* widwt = (const float*)d_in[10];
    const float* bidwt = (const float*)d_in[11];
    const float* wproj = (const float*)d_in[12];
    float* out = (float*)d_out;

    char* W8 = (char*)d_ws;
    const size_t SLOT = 16777216;
    short* slotA = (short*)(W8);              // D0 -> I0
    short* slotB = (short*)(W8 + SLOT);       // D1
    short* slotC = (short*)(W8 + 2 * SLOT);   // Qb -> I2
    short* slotD = (short*)(W8 + 3 * SLOT);   // Kb
    char* P = W8 + 4 * SLOT;
    short* wF1    = (short*)P; P += 2 * 655360;
    short* wF2c   = (short*)P; P += 2 * 40960;
    short* wFk    = (short*)P; P += 2 * 65536;
    short* wpF    = (short*)P; P += 2 * 4096;
    short* wFq    = (short*)P; P += 2 * 4096;
    short* WfoldF = (short*)P; P += 2 * 131072;
    float* scr    = (float*)P;
    float* qss   = scr;
    float* kss   = scr + 128;
    float* gram  = scr + 256;
    float* attn  = scr + 2304;
    float* bfold = scr + 4352;

    prep_all<<<3009, 256, 0, stream>>>(wdwt, widwt, w2, wproj, w1,
                                       wF1, wF2c, wFk, wpF, wFq, scr);

    // fused DWT + Q conv (x read once): D0 -> slotA, Qb -> slotC
    dwtq_kernel<<<dim3(2, 128, 2), 256, 0, stream>>>(x, wFq, b1, slotA, slotC);

    // DWT-branch 3x3 conv — v13: reg-dbuf weights + barrier-per-chunk (16 vs 80)
    conv3_v13<<<dim3(64, 4, 2), 256, 0, stream>>>(slotA, wF1, bdwt, slotB);

    // K conv + gram (frees slotC after gram)
    kconv_mfma<<<dim3(4, 64, 2), 256, 0, stream>>>(slotB, wFk, b2, slotD);
    gram_mfma<<<dim3(128, 2), 256, 0, stream>>>(slotC, slotD, qss, kss, gram);

    // IDWT branch (slotA reused for I0, slotC reused for I2)
    idwt_kernel<<<8192, 256, 0, stream>>>(slotB, slotA);
    // idwt-branch 3x3 conv — v14: same barrier diet
    conv3_v14<<<dim3(128, 2, 2), 256, 0, stream>>>(slotA, wF2c, bidwt, slotC);

    // softmax -> fold
    attn_kernel<<<8, 256, 0, stream>>>(gram, qss, kss, temp, attn);
    fold_v2<<<dim3(16, 8), 256, 0, stream>>>(attn, w3, b3, wproj, WfoldF, bfold);

    // fused (attn·V + proj) + idwt-branch proj
    final_mfma<<<dim3(256, 2), 256, 0, stream>>>(slotB, slotC, WfoldF, wpF, bfold, out);
}

// Round 11
// 243.706 us; speedup vs baseline: 1.2128x; 1.0169x over previous
//
#include <hip/hip_runtime.h>
#include <hip/hip_bf16.h>

typedef __hip_bfloat16 bf16;
typedef __attribute__((ext_vector_type(8))) short short8;
typedef __attribute__((ext_vector_type(4))) float f32x4;
typedef unsigned short u16;
typedef unsigned int u32;

static __device__ __forceinline__ u16 f2bs(float f) {
    bf16 h = __float2bfloat16(f);
    return *reinterpret_cast<u16*>(&h);
}
static __device__ __forceinline__ float bs2f(u16 u) {
    union { float f; u32 i; } x; x.i = ((u32)u) << 16; return x.f;
}
static __device__ __forceinline__ uint4 pack8(const u16* p) {
    uint4 v;
    v.x = (u32)p[0] | ((u32)p[1] << 16);
    v.y = (u32)p[2] | ((u32)p[3] << 16);
    v.z = (u32)p[4] | ((u32)p[5] << 16);
    v.w = (u32)p[6] | ((u32)p[7] << 16);
    return v;
}
// async global->LDS DMA, 16B per lane. Per-lane GLOBAL address, wave-uniform LDS base.
static __device__ __forceinline__ void gl16(const short* g, short* l) {
    __builtin_amdgcn_global_load_lds(
        (const __attribute__((address_space(1))) u32*)(g),
        (__attribute__((address_space(3))) u32*)(l), 16, 0, 0);
}

// =================== weight prep ===================
// classic layout [ocblk][ch][pr][mt][lane][j] — for ocblk=1 (C=64) this is already
// phase-major: phase P=(ch*5+pr) at offset P*2048 shorts (used by conv3_v14)
__device__ __forceinline__ void prep3_body(const float* __restrict__ w, short* __restrict__ wF,
                                           int C, int idx) {
    int j = idx & 7;
    int lane = (idx >> 3) & 63;
    int mt = (idx >> 9) & 3;
    int rest = idx >> 11;
    int pair = rest % 5;
    int bo = rest / 5;
    int nchunks = C / 16;
    int ch = bo % nchunks;
    int ocblk = bo / nchunks;
    int s = ((lane >> 4) * 8 + j);
    int tp = 2 * pair + (s >> 4);
    int ci = ch * 16 + (s & 15);
    int oc = ocblk * 64 + mt * 16 + (lane & 15);
    float v = (tp <= 8) ? w[((size_t)(oc * C + ci)) * 9 + tp] : 0.f;
    wF[idx] = (short)f2bs(v);
}
// phase-major layout [ch][pr][ocg][mt][lane][j] for conv3_v13 (4KB per (phase,ocg))
__device__ __forceinline__ void prep3_chpr(const float* __restrict__ w, short* __restrict__ wF,
                                           int idx) {
    int j = idx & 7;
    int lane = (idx >> 3) & 63;
    int mt = (idx >> 9) & 3;
    int rest = idx >> 11;
    int ocg = rest & 3;
    int r2 = rest >> 2;
    int pr = r2 % 5;
    int ch = r2 / 5;
    int s = ((lane >> 4) * 8 + j);
    int tp = 2 * pr + (s >> 4);
    int ci = ch * 16 + (s & 15);
    int oc = ocg * 64 + mt * 16 + (lane & 15);
    float v = (tp <= 8) ? w[((size_t)(oc * 256 + ci)) * 9 + tp] : 0.f;
    wF[idx] = (short)f2bs(v);
}
__device__ __forceinline__ void prep1_body(const float* __restrict__ w, short* __restrict__ wF,
                                           int Cin, int cioff, int nchunks, int idx) {
    int j = idx & 7;
    int lane = (idx >> 3) & 63;
    int mt = (idx >> 9) & 3;
    int bo = idx >> 11;
    int ch = bo % nchunks;
    int ocblk = bo / nchunks;
    int s = (lane >> 4) * 8 + j;
    int ci = cioff + ch * 32 + s;
    int oc = ocblk * 64 + mt * 16 + (lane & 15);
    wF[idx] = (short)f2bs(w[(size_t)oc * Cin + ci]);
}

__global__ __launch_bounds__(256) void prep_all(
        const float* __restrict__ wdwt, const float* __restrict__ widwt,
        const float* __restrict__ w2, const float* __restrict__ wproj,
        const float* __restrict__ w1,
        short* __restrict__ wF1, short* __restrict__ wF2c, short* __restrict__ wFk,
        short* __restrict__ wpF, short* __restrict__ wFq, float* __restrict__ scr) {
    int blk = blockIdx.x;
    int tid = threadIdx.x;
    if (blk < 2560) {
        prep3_chpr(wdwt, wF1, blk * 256 + tid);
    } else if (blk < 2720) {
        prep3_body(widwt, wF2c, 64, (blk - 2560) * 256 + tid);
    } else if (blk < 2976) {
        prep1_body(w2, wFk, 256, 0, 8, (blk - 2720) * 256 + tid);
    } else if (blk < 2992) {
        prep1_body(wproj, wpF, 128, 64, 2, (blk - 2976) * 256 + tid);
    } else if (blk < 3008) {
        prep1_body(w1, wFq, 64, 0, 2, (blk - 2992) * 256 + tid);
    } else {
        for (int i = tid; i < 4864; i += 256) scr[i] = 0.f;
    }
}

// =================== fused Haar DWT + Q conv ===================
__global__ __launch_bounds__(256) void dwtq_kernel(
        const float* __restrict__ x, const short* __restrict__ wFq,
        const float* __restrict__ b1, short* __restrict__ d0, short* __restrict__ outQ) {
    __shared__ short ls[256 * 72];
    int tid = threadIdx.x;
    int lane = tid & 63, wv = tid >> 6;
    int q = lane >> 4, pl = lane & 15;
    int xh = blockIdx.x;
    int y2 = blockIdx.y;
    int b = blockIdx.z;
    int x0 = xh * 128;

    #pragma unroll
    for (int k2 = 0; k2 < 16; ++k2) {
        int u = k2 * 256 + tid;
        int ch = u & 63;
        int xu = (u >> 6) & 31;
        int r = (u >> 11) & 1;
        float4 v = *(const float4*)(x + (((size_t)(b * 64 + ch) * 256 + (2 * y2 + r))) * 256 + x0 + xu * 4);
        ls[(r * 128 + xu * 4 + 0) * 72 + ch] = (short)f2bs(v.x);
        ls[(r * 128 + xu * 4 + 1) * 72 + ch] = (short)f2bs(v.y);
        ls[(r * 128 + xu * 4 + 2) * 72 + ch] = (short)f2bs(v.z);
        ls[(r * 128 + xu * 4 + 3) * 72 + ch] = (short)f2bs(v.w);
    }
    __syncthreads();

    f32x4 acc[4][4];
    #pragma unroll
    for (int mt = 0; mt < 4; ++mt)
        #pragma unroll
        for (int nt = 0; nt < 4; ++nt)
            acc[mt][nt] = (f32x4){0.f, 0.f, 0.f, 0.f};
    #pragma unroll
    for (int chk = 0; chk < 2; ++chk) {
        short8 af[4];
        #pragma unroll
        for (int mt = 0; mt < 4; ++mt)
            af[mt] = *(const short8*)(wFq + (chk * 4 + mt) * 512 + lane * 8);
        #pragma unroll
        for (int nt = 0; nt < 4; ++nt) {
            int p = wv * 64 + nt * 16 + pl;
            short8 bfr = *(const short8*)(ls + p * 72 + chk * 32 + q * 8);
            #pragma unroll
            for (int mt = 0; mt < 4; ++mt)
                acc[mt][nt] = __builtin_amdgcn_mfma_f32_16x16x32_bf16(af[mt], bfr, acc[mt][nt], 0, 0, 0);
        }
    }
    #pragma unroll
    for (int mt = 0; mt < 4; ++mt) {
        int ocb = mt * 16 + q * 4;
        float4 bi = *(const float4*)(b1 + ocb);
        float bia[4] = {bi.x, bi.y, bi.z, bi.w};
        #pragma unroll
        for (int nt = 0; nt < 4; ++nt) {
            int p = wv * 64 + nt * 16 + pl;
            int n = (2 * y2 + (p >> 7)) * 256 + x0 + (p & 127);
            #pragma unroll
            for (int r = 0; r < 4; ++r)
                outQ[((size_t)(b * 64 + ocb + r)) * 65536 + n] = (short)f2bs(acc[mt][nt][r] + bia[r]);
        }
    }

    int xl = tid >> 2;
    int cg = tid & 3;
    int c0 = cg * 16;
    u16 obuf[4][16];
    #pragma unroll
    for (int cl = 0; cl < 16; ++cl) {
        int c = c0 + cl;
        float a  = bs2f(ls[(2 * xl) * 72 + c]);
        float bb = bs2f(ls[(2 * xl + 1) * 72 + c]);
        float c2 = bs2f(ls[(128 + 2 * xl) * 72 + c]);
        float dd = bs2f(ls[(128 + 2 * xl + 1) * 72 + c]);
        obuf[0][cl] = f2bs((a - bb + c2 - dd) * 0.5f);  // lh
        obuf[1][cl] = f2bs((a + bb - c2 - dd) * 0.5f);  // hl
        obuf[2][cl] = f2bs((a - bb - c2 + dd) * 0.5f);  // hh
        obuf[3][cl] = f2bs((a + bb + c2 + dd) * 0.5f);  // ll
    }
    int xd = xh * 64 + xl;
    size_t P = ((size_t)(b * 128 + y2) * 128 + xd) * 256;
    #pragma unroll
    for (int g = 0; g < 4; ++g) {
        *(uint4*)&d0[P + g * 64 + c0]     = pack8(&obuf[g][0]);
        *(uint4*)&d0[P + g * 64 + c0 + 8] = pack8(&obuf[g][8]);
    }
}

// =================== Haar IDWT ===================
__global__ __launch_bounds__(256) void idwt_kernel(const short* __restrict__ d1, short* __restrict__ i0) {
    int tid = threadIdx.x;
    int lane = tid & 63;
    int p = blockIdx.x * 4 + (tid >> 6);
    int b = p >> 14, m = p & 16383;
    ushort4 v = *(const ushort4*)(d1 + ((size_t)(b * 16384 + m)) * 256 + 4 * lane);
    float yl = bs2f(v.x), lh = bs2f(v.y), hl = bs2f(v.z), hh = bs2f(v.w);
    float a_ = (yl + lh + hl + hh) * 0.5f;
    float b_ = (yl - lh + hl - hh) * 0.5f;
    float c_ = (yl + lh - hl - hh) * 0.5f;
    float d_ = (yl - lh - hl + hh) * 0.5f;
    int y = m >> 7, xx = m & 127;
    u16* o = (u16*)i0;
    size_t base = ((size_t)(b * 256 + 2 * y) * 256 + 2 * xx) * 64 + lane;
    o[base] = f2bs(a_);
    o[base + 64] = f2bs(b_);
    o[base + 256 * 64] = f2bs(c_);
    o[base + 256 * 64 + 64] = f2bs(d_);
}

// =================== 3x3 conv v13 (C=256): reg-dbuf weights, barrier/chunk, setprio ===
#define PHASE_NB11(P, WC, WN)                                                     \
    {                                                                             \
        const int P_ = (P);                                                       \
        const int ch_ = P_ / 5;                                                   \
        const int pr_ = P_ - ch_ * 5;                                             \
        if (P_ + 1 < 80) {                                                        \
            const short* wn = wF + ((size_t)((P_ + 1) * 4 + ocg)) * 2048;         \
            _Pragma("unroll")                                                     \
            for (int mt = 0; mt < 4; ++mt)                                        \
                WN[mt] = *(const short8*)(wn + mt * 512 + lane * 8);              \
        }                                                                         \
        if (pr_ == 0 && ch_ < 15) {                                               \
            short* id = ibuf[(ch_ + 1) & 1];                                      \
            _Pragma("unroll")                                                     \
            for (int k2 = 0; k2 < UPT; ++k2)                                      \
                if (act[k2]) gl16(gp[k2] + (ch_ + 1) * 16, id + ibo[k2]);         \
        }                                                                         \
        const short* ib = ibuf[ch_ & 1];                                          \
        int t1 = 2 * pr_ + (q >> 1);                                              \
        if (t1 > 8) t1 = 8;                                                       \
        int ti = (t1 >= 6) ? 2 : ((t1 >= 3) ? 1 : 0);                             \
        int tj = t1 - ti * 3;                                                     \
        __builtin_amdgcn_s_setprio(1);                                            \
        _Pragma("unroll")                                                         \
        for (int nt = 0; nt < 4; ++nt) {                                          \
            int i = colbase + nt * 16 + pl + tj;                                  \
            short8 bfr = *(const short8*)(ib + ((ti + orow) * Wp + i) * 16 + (q & 1) * 8); \
            _Pragma("unroll")                                                     \
            for (int mt = 0; mt < 4; ++mt)                                        \
                acc[mt][nt] = __builtin_amdgcn_mfma_f32_16x16x32_bf16(WC[mt], bfr, acc[mt][nt], 0, 0, 0); \
        }                                                                         \
        __builtin_amdgcn_s_setprio(0);                                            \
    }

__global__ __launch_bounds__(256) void conv3_v13(
        const short* __restrict__ in, const short* __restrict__ wF,
        const float* __restrict__ bias, short* __restrict__ out) {
    constexpr int C = 256, W = 128, H = 128;
    constexpr int Wp = W + 2;              // 130 staged cols
    constexpr int UNITS = 4 * Wp * 2;      // 1040 16B-units per input chunk (4 rows)
    constexpr int UPT = 5;                 // ceil(1040/256)
    __shared__ short ibuf[2][4 * Wp * 16]; // 2 x 16.64 KB (input only; weights in regs)

    int tid = threadIdx.x;
    int lane = tid & 63, wv = tid >> 6;
    int q = lane >> 4, pl = lane & 15;
    int ocg = blockIdx.y;
    int bx = blockIdx.x;                   // row-pair index 0..63
    int rp = ((bx & 7) << 3) | (bx >> 3);  // bijective 8x8: XCD k owns row-pairs [8k,8k+8)
    int y0 = rp * 2;
    int b = blockIdx.z;
    int orow = wv >> 1;                    // which of the 2 output rows
    int colbase = (wv & 1) * 64;           // which 64-px half

    const short* gp[UPT];
    int ibo[UPT];
    bool act[UPT];
    #pragma unroll
    for (int k2 = 0; k2 < UPT; ++k2) {
        int u = k2 * 256 + tid;
        act[k2] = (u < UNITS);
        int uu = act[k2] ? u : 0;
        int r = uu / (Wp * 2);
        int rem = uu - r * (Wp * 2);
        int px = rem >> 1, hf = rem & 1;
        int ry = y0 - 1 + r;
        if (ry < 0) ry = 1;
        if (ry >= H) ry = 2 * H - 2 - ry;
        int rx = px - 1;
        if (rx < 0) rx = 1;
        if (rx >= W) rx = W - 2;
        gp[k2] = in + ((b * H + ry) * W + rx) * C + hf * 8;
        ibo[k2] = (k2 * 256 + wv * 64) * 8;   // wave-uniform LDS base (lane*16B auto)
    }

    f32x4 acc[4][4];
    #pragma unroll
    for (int mt = 0; mt < 4; ++mt)
        #pragma unroll
        for (int nt = 0; nt < 4; ++nt)
            acc[mt][nt] = (f32x4){0.f, 0.f, 0.f, 0.f};

    short8 wA[4], wB[4];
    {
        const short* w0 = wF + ((size_t)(0 * 4 + ocg)) * 2048;
        #pragma unroll
        for (int mt = 0; mt < 4; ++mt)
            wA[mt] = *(const short8*)(w0 + mt * 512 + lane * 8);
    }
    #pragma unroll
    for (int k2 = 0; k2 < UPT; ++k2)
        if (act[k2]) gl16(gp[k2], &ibuf[0][ibo[k2]]);
    __syncthreads();

    #pragma unroll 1
    for (int cp = 0; cp < 8; ++cp) {
        int base = cp * 10;
        PHASE_NB11(base + 0, wA, wB)
        PHASE_NB11(base + 1, wB, wA)
        PHASE_NB11(base + 2, wA, wB)
        PHASE_NB11(base + 3, wB, wA)
        PHASE_NB11(base + 4, wA, wB)
        __syncthreads();
        PHASE_NB11(base + 5, wB, wA)
        PHASE_NB11(base + 6, wA, wB)
        PHASE_NB11(base + 7, wB, wA)
        PHASE_NB11(base + 8, wA, wB)
        PHASE_NB11(base + 9, wB, wA)
        __syncthreads();
    }

    int yout = y0 + orow;
    #pragma unroll
    for (int mt = 0; mt < 4; ++mt) {
        int ocb = ocg * 64 + mt * 16 + q * 4;
        float4 bi = *(const float4*)(bias + ocb);
        float bia[4] = {bi.x, bi.y, bi.z, bi.w};
        #pragma unroll
        for (int nt = 0; nt < 4; ++nt) {
            int xl = colbase + nt * 16 + pl;
            ushort4 pk;
            float v0 = acc[mt][nt][0] + bia[0]; pk.x = f2bs(v0 >= 0.f ? v0 : 0.01f * v0);
            float v1 = acc[mt][nt][1] + bia[1]; pk.y = f2bs(v1 >= 0.f ? v1 : 0.01f * v1);
            float v2 = acc[mt][nt][2] + bia[2]; pk.z = f2bs(v2 >= 0.f ? v2 : 0.01f * v2);
            float v3 = acc[mt][nt][3] + bia[3]; pk.w = f2bs(v3 >= 0.f ? v3 : 0.01f * v3);
            *(ushort4*)(out + (((size_t)(b * H + yout)) * W + xl) * C + ocb) = pk;
        }
    }
}

// =================== 3x3 conv v14 (C=64, H=W=256): same schedule ===================
#define PHASE_NB12(P, WC, WN)                                                     \
    {                                                                             \
        const int P_ = (P);                                                       \
        const int ch_ = P_ / 5;                                                   \
        const int pr_ = P_ - ch_ * 5;                                             \
        if (P_ + 1 < 20) {                                                        \
            const short* wn = wF + ((size_t)(P_ + 1)) * 2048;                     \
            _Pragma("unroll")                                                     \
            for (int mt = 0; mt < 4; ++mt)                                        \
                WN[mt] = *(const short8*)(wn + mt * 512 + lane * 8);              \
        }                                                                         \
        if (pr_ == 0 && ch_ < 3) {                                                \
            short* id = ibuf[(ch_ + 1) & 1];                                      \
            _Pragma("unroll")                                                     \
            for (int k2 = 0; k2 < UPT; ++k2)                                      \
                if (act[k2]) gl16(gp[k2] + (ch_ + 1) * 16, id + ibo[k2]);         \
        }                                                                         \
        const short* ib = ibuf[ch_ & 1];                                          \
        int t1 = 2 * pr_ + (q >> 1);                                              \
        if (t1 > 8) t1 = 8;                                                      \
        int ti = (t1 >= 6) ? 2 : ((t1 >= 3) ? 1 : 0);                             \
        int tj = t1 - ti * 3;                                                     \
        __builtin_amdgcn_s_setprio(1);                                            \
        _Pragma("unroll")                                                         \
        for (int nt = 0; nt < 4; ++nt) {                                          \
            int i = colbase + nt * 16 + pl + tj;                                  \
            short8 bfr = *(const short8*)(ib + ((ti + orow) * Wp + i) * 16 + (q & 1) * 8); \
            _Pragma("unroll")                                                     \
            for (int mt = 0; mt < 4; ++mt)                                        \
                acc[mt][nt] = __builtin_amdgcn_mfma_f32_16x16x32_bf16(WC[mt], bfr, acc[mt][nt], 0, 0, 0); \
        }                                                                         \
        __builtin_amdgcn_s_setprio(0);                                            \
    }

__global__ __launch_bounds__(256) void conv3_v14(
        const short* __restrict__ in, const short* __restrict__ wF,
        const float* __restrict__ bias, short* __restrict__ out) {
    constexpr int C = 64, W = 256, H = 256;
    constexpr int Wp = 130;                // 128-col window + halo
    constexpr int UNITS = 4 * Wp * 2;      // 1040 16B-units per input chunk (4 rows)
    constexpr int UPT = 5;                 // ceil(1040/256)
    __shared__ short ibuf[2][4 * Wp * 16]; // 2 x 16.64 KB

    int tid = threadIdx.x;
    int lane = tid & 63, wv = tid >> 6;
    int q = lane >> 4, pl = lane & 15;
    int bx = blockIdx.x;                   // row-pair index 0..127
    int rp = ((bx & 7) << 4) | (bx >> 3);  // XCD k owns row-pairs [16k,16k+16)
    int y0 = rp * 2;
    int xh = blockIdx.y;
    int x0 = xh * 128;
    int b = blockIdx.z;
    int orow = wv >> 1;                    // which of the 2 output rows
    int colbase = (wv & 1) * 64;           // which 64-px half

    const short* gp[UPT];
    int ibo[UPT];
    bool act[UPT];
    #pragma unroll
    for (int k2 = 0; k2 < UPT; ++k2) {
        int u = k2 * 256 + tid;
        act[k2] = (u < UNITS);
        int uu = act[k2] ? u : 0;
        int r = uu / (Wp * 2);
        int rem = uu - r * (Wp * 2);
        int px = rem >> 1, hf = rem & 1;
        int ry = y0 - 1 + r;
        if (ry < 0) ry = 1;
        if (ry >= H) ry = 2 * H - 2 - ry;
        int rx = x0 - 1 + px;
        if (rx < 0) rx = 1;
        if (rx >= W) rx = 2 * W - 2 - rx;
        gp[k2] = in + ((b * H + ry) * W + rx) * C + hf * 8;
        ibo[k2] = (k2 * 256 + wv * 64) * 8;   // wave-uniform LDS base (lane*16B auto)
    }

    f32x4 acc[4][4];
    #pragma unroll
    for (int mt = 0; mt < 4; ++mt)
        #pragma unroll
        for (int nt = 0; nt < 4; ++nt)
            acc[mt][nt] = (f32x4){0.f, 0.f, 0.f, 0.f};

    short8 wA[4], wB[4];
    {
        #pragma unroll
        for (int mt = 0; mt < 4; ++mt)
            wA[mt] = *(const short8*)(wF + mt * 512 + lane * 8);
    }
    #pragma unroll
    for (int k2 = 0; k2 < UPT; ++k2)
        if (act[k2]) gl16(gp[k2], &ibuf[0][ibo[k2]]);
    __syncthreads();

    #pragma unroll 1
    for (int cp = 0; cp < 2; ++cp) {
        int base = cp * 10;
        PHASE_NB12(base + 0, wA, wB)
        PHASE_NB12(base + 1, wB, wA)
        PHASE_NB12(base + 2, wA, wB)
        PHASE_NB12(base + 3, wB, wA)
        PHASE_NB12(base + 4, wA, wB)
        __syncthreads();
        PHASE_NB12(base + 5, wB, wA)
        PHASE_NB12(base + 6, wA, wB)
        PHASE_NB12(base + 7, wB, wA)
        PHASE_NB12(base + 8, wA, wB)
        PHASE_NB12(base + 9, wB, wA)
        __syncthreads();
    }

    int yout = y0 + orow;
    #pragma unroll
    for (int mt = 0; mt < 4; ++mt) {
        int ocb = mt * 16 + q * 4;
        float4 bi = *(const float4*)(bias + ocb);
        float bia[4] = {bi.x, bi.y, bi.z, bi.w};
        #pragma unroll
        for (int nt = 0; nt < 4; ++nt) {
            int xl = x0 + colbase + nt * 16 + pl;
            ushort4 pk;
            float v0 = acc[mt][nt][0] + bia[0]; pk.x = f2bs(v0 >= 0.f ? v0 : 0.01f * v0);
            float v1 = acc[mt][nt][1] + bia[1]; pk.y = f2bs(v1 >= 0.f ? v1 : 0.01f * v1);
            float v2 = acc[mt][nt][2] + bia[2]; pk.z = f2bs(v2 >= 0.f ? v2 : 0.01f * v2);
            float v3 = acc[mt][nt][3] + bia[3]; pk.w = f2bs(v3 >= 0.f ? v3 : 0.01f * v3);
            *(ushort4*)(out + (((size_t)(b * H + yout)) * W + xl) * C + ocb) = pk;
        }
    }
}

// =================== K conv 1x1 MFMA ===================
__global__ __launch_bounds__(256) void kconv_mfma(
        const short* __restrict__ in, const short* __restrict__ wF,
        const float* __restrict__ bias, short* __restrict__ outK) {
    __shared__ short inS[8192];
    int tid = threadIdx.x;
    int lane = tid & 63, wv = tid >> 6;
    int q = lane >> 4, pl = lane & 15;
    int ocblk = blockIdx.x;
    int m0 = blockIdx.y * 256;
    int b = blockIdx.z;
    int px0w = wv * 64;
    f32x4 acc[4][4];
    #pragma unroll
    for (int mt = 0; mt < 4; ++mt)
        #pragma unroll
        for (int nt = 0; nt < 4; ++nt)
            acc[mt][nt] = (f32x4){0.f, 0.f, 0.f, 0.f};

    for (int ch = 0; ch < 8; ++ch) {
        if (ch) __syncthreads();
        const short* src = in + ((size_t)(b * 16384 + m0)) * 256 + ch * 32;
        for (int t = tid; t < 1024; t += 256) {
            int pix = t >> 2, hf = t & 3;
            *(uint4*)(inS + pix * 32 + hf * 8) = *(const uint4*)(src + (size_t)pix * 256 + hf * 8);
        }
        short8 af[4];
        #pragma unroll
        for (int mt = 0; mt < 4; ++mt)
            af[mt] = *(const short8*)(wF + ((size_t)(ocblk * 8 + ch)) * 2048 + mt * 512 + lane * 8);
        __syncthreads();
        #pragma unroll
        for (int nt = 0; nt < 4; ++nt) {
            short8 bfr = *(const short8*)(inS + (px0w + nt * 16 + pl) * 32 + q * 8);
            #pragma unroll
            for (int mt = 0; mt < 4; ++mt)
                acc[mt][nt] = __builtin_amdgcn_mfma_f32_16x16x32_bf16(af[mt], bfr, acc[mt][nt], 0, 0, 0);
        }
    }
    #pragma unroll
    for (int mt = 0; mt < 4; ++mt) {
        int ocb = ocblk * 64 + mt * 16 + q * 4;
        float4 bi = *(const float4*)(bias + ocb);
        float bia[4] = {bi.x, bi.y, bi.z, bi.w};
        #pragma unroll
        for (int nt = 0; nt < 4; ++nt) {
            int n = m0 + px0w + nt * 16 + pl;
            #pragma unroll
            for (int r = 0; r < 4; ++r) {
                int co = ocb + r;
                outK[((size_t)(b * 64 + (co >> 2))) * 65536 + (co & 3) * 16384 + n] =
                    (short)f2bs(acc[mt][nt][r] + bia[r]);
            }
        }
    }
}

// =================== Gram via MFMA: per-head 16x16 Q.K^T + row norms ===================
__global__ __launch_bounds__(256) void gram_mfma(
        const short* __restrict__ Q, const short* __restrict__ K,
        float* __restrict__ qss, float* __restrict__ kss, float* __restrict__ gram) {
    int tid = threadIdx.x;
    int lane = tid & 63, h = tid >> 6;
    int q = lane >> 4, m = lane & 15;
    int b = blockIdx.y;
    int n0 = blockIdx.x * 512;
    const short* qrow = Q + ((size_t)(b * 64 + h * 16 + m)) * 65536 + n0 + q * 8;
    const short* krow = K + ((size_t)(b * 64 + h * 16 + m)) * 65536 + n0 + q * 8;
    f32x4 acc = (f32x4){0.f, 0.f, 0.f, 0.f};
    float sq = 0.f, sk = 0.f;
    #pragma unroll 4
    for (int it = 0; it < 16; ++it) {
        short8 aq = *(const short8*)(qrow + it * 32);
        short8 ak = *(const short8*)(krow + it * 32);
        acc = __builtin_amdgcn_mfma_f32_16x16x32_bf16(aq, ak, acc, 0, 0, 0);
        #pragma unroll
        for (int j = 0; j < 8; ++j) {
            float fq = bs2f((u16)aq[j]);
            float fk = bs2f((u16)ak[j]);
            sq += fq * fq;
            sk += fk * fk;
        }
    }
    sq += __shfl_xor(sq, 16); sq += __shfl_xor(sq, 32);
    sk += __shfl_xor(sk, 16); sk += __shfl_xor(sk, 32);
    if (q == 0) {
        atomicAdd(&qss[b * 64 + h * 16 + m], sq);
        atomicAdd(&kss[b * 64 + h * 16 + m], sk);
    }
    #pragma unroll
    for (int r = 0; r < 4; ++r) {
        int c = q * 4 + r;   // row of D
        atomicAdd(&gram[b * 1024 + h * 256 + c * 16 + m], acc[r]);
    }
}

// =================== fold v3: softmax fused in (attn_kernel removed) ===================
__global__ __launch_bounds__(256) void fold_v3(
        const float* __restrict__ gram, const float* __restrict__ qss,
        const float* __restrict__ kss, const float* __restrict__ temp,
        const float* __restrict__ w3, const float* __restrict__ b3,
        const float* __restrict__ wproj,
        short* __restrict__ WfoldF, float* __restrict__ bfold) {
    __shared__ float attn_s[1024];
    __shared__ float rmax[64], rsum[64];
    __shared__ float wp_s[64][65];
    __shared__ float Aeff_s[64][17];
    __shared__ float beff[64];
    int bt = blockIdx.y;
    int b = bt >> 2, t = bt & 3;
    int ci0 = blockIdx.x * 16;
    int tid = threadIdx.x;
    // logits
    #pragma unroll
    for (int i = 0; i < 4; ++i) {
        int idx = tid + i * 256;
        int h = idx >> 8, c = (idx >> 4) & 15, d = idx & 15;
        float qn = fmaxf(sqrtf(qss[b * 64 + h * 16 + c]), 1e-12f);
        float kn = fmaxf(sqrtf(kss[b * 64 + h * 16 + d]), 1e-12f);
        attn_s[idx] = gram[b * 1024 + idx] / (qn * kn) * temp[h];
    }
    #pragma unroll
    for (int i = 0; i < 16; ++i) {
        int idx = tid + i * 256;
        int co = idx >> 6, C = idx & 63;
        wp_s[co][C] = wproj[co * 128 + C];
    }
    __syncthreads();
    if (tid < 64) {
        float m = -1e30f;
        #pragma unroll
        for (int d = 0; d < 16; ++d) m = fmaxf(m, attn_s[tid * 16 + d]);
        float s = 0.f;
        #pragma unroll
        for (int d = 0; d < 16; ++d) s += expf(attn_s[tid * 16 + d] - m);
        rmax[tid] = m;
        rsum[tid] = s;
    }
    __syncthreads();
    #pragma unroll
    for (int i = 0; i < 4; ++i) {
        int idx = tid + i * 256;
        int row = idx >> 4;
        attn_s[idx] = expf(attn_s[idx] - rmax[row]) / rsum[row];
    }
    __syncthreads();
    #pragma unroll
    for (int pass = 0; pass < 4; ++pass) {
        int el = pass * 256 + tid;
        int C = el >> 4, ci_l = el & 15;
        int h = C >> 4, c = C & 15;
        float s = 0.f;
        #pragma unroll
        for (int d = 0; d < 16; ++d)
            s += attn_s[h * 256 + c * 16 + d] * w3[(size_t)(4 * (h * 16 + d) + t) * 256 + ci0 + ci_l];
        Aeff_s[C][ci_l] = s;
    }
    if (blockIdx.x == 0 && tid < 64) {
        int h = tid >> 4, c = tid & 15;
        float s = 0.f;
        #pragma unroll
        for (int d = 0; d < 16; ++d)
            s += attn_s[h * 256 + c * 16 + d] * b3[4 * (h * 16 + d) + t];
        beff[tid] = s;
    }
    __syncthreads();
    #pragma unroll
    for (int pass = 0; pass < 4; ++pass) {
        int el = pass * 256 + tid;
        int ci_l = el >> 6, co = el & 63;
        float s = 0.f;
        #pragma unroll
        for (int C = 0; C < 64; ++C) s += wp_s[co][C] * Aeff_s[C][ci_l];
        int ci = ci0 + ci_l;
        int chk = ci >> 5;
        int s5 = ci & 31;
        int j = s5 & 7;
        int lane2 = (((s5 >> 3) << 4)) | (co & 15);
        int mt = co >> 4;
        WfoldF[(((size_t)(bt * 8 + chk) * 4 + mt)) * 512 + lane2 * 8 + j] = (short)f2bs(s);
    }
    if (blockIdx.x == 0 && tid < 64) {
        float s = 0.f;
        #pragma unroll
        for (int C = 0; C < 64; ++C) s += wp_s[tid][C] * beff[C];
        bfold[bt * 64 + tid] = s;
    }
}

// =================== final: out = Wfold[b,t]·D1 + bfold + Wp2·I2, fp32 out ===================
__global__ __launch_bounds__(256) void final_mfma(
        const short* __restrict__ D1, const short* __restrict__ I2,
        const short* __restrict__ WfoldF, const short* __restrict__ wpF,
        const float* __restrict__ bfold, float* __restrict__ out) {
    __shared__ short inS[8192];
    int tid = threadIdx.x;
    int lane = tid & 63, wv = tid >> 6;
    int q = lane >> 4, pl = lane & 15;
    int n0 = blockIdx.x * 256;
    int b = blockIdx.y;
    int t = n0 >> 14, m0 = n0 & 16383, bt = b * 4 + t;
    int px0w = wv * 64;
    f32x4 acc[4][4];
    #pragma unroll
    for (int mt = 0; mt < 4; ++mt) {
        float4 bf4 = *(const float4*)(bfold + bt * 64 + mt * 16 + q * 4);
        #pragma unroll
        for (int nt = 0; nt < 4; ++nt)
            acc[mt][nt] = (f32x4){bf4.x, bf4.y, bf4.z, bf4.w};
    }
    for (int ch = 0; ch < 8; ++ch) {
        if (ch) __syncthreads();
        const short* src = D1 + ((size_t)(b * 16384 + m0)) * 256 + ch * 32;
        for (int tt = tid; tt < 1024; tt += 256) {
            int pix = tt >> 2, hf = tt & 3;
            *(uint4*)(inS + pix * 32 + hf * 8) = *(const uint4*)(src + (size_t)pix * 256 + hf * 8);
        }
        short8 af[4];
        #pragma unroll
        for (int mt = 0; mt < 4; ++mt)
            af[mt] = *(const short8*)(WfoldF + ((size_t)(bt * 8 + ch)) * 2048 + mt * 512 + lane * 8);
        __syncthreads();
        #pragma unroll
        for (int nt = 0; nt < 4; ++nt) {
            short8 bfr = *(const short8*)(inS + (px0w + nt * 16 + pl) * 32 + q * 8);
            #pragma unroll
            for (int mt = 0; mt < 4; ++mt)
                acc[mt][nt] = __builtin_amdgcn_mfma_f32_16x16x32_bf16(af[mt], bfr, acc[mt][nt], 0, 0, 0);
        }
    }
    for (int ch = 0; ch < 2; ++ch) {
        __syncthreads();
        const short* src = I2 + ((size_t)(b * 65536 + n0)) * 64 + ch * 32;
        for (int tt = tid; tt < 1024; tt += 256) {
            int pix = tt >> 2, hf = tt & 3;
            *(uint4*)(inS + pix * 32 + hf * 8) = *(const uint4*)(src + (size_t)pix * 64 + hf * 8);
        }
        short8 af[4];
        #pragma unroll
        for (int mt = 0; mt < 4; ++mt)
            af[mt] = *(const short8*)(wpF + (size_t)ch * 2048 + mt * 512 + lane * 8);
        __syncthreads();
        #pragma unroll
        for (int nt = 0; nt < 4; ++nt) {
            short8 bfr = *(const short8*)(inS + (px0w + nt * 16 + pl) * 32 + q * 8);
            #pragma unroll
            for (int mt = 0; mt < 4; ++mt)
                acc[mt][nt] = __builtin_amdgcn_mfma_f32_16x16x32_bf16(af[mt], bfr, acc[mt][nt], 0, 0, 0);
        }
    }
    #pragma unroll
    for (int mt = 0; mt < 4; ++mt) {
        #pragma unroll
        for (int nt = 0; nt < 4; ++nt) {
            int n = n0 + px0w + nt * 16 + pl;
            #pragma unroll
            for (int r = 0; r < 4; ++r) {
                int co = mt * 16 + q * 4 + r;
                out[((size_t)(b * 64 + co)) * 65536 + n] = acc[mt][nt][r];
            }
        }
    }
}

extern "C" void kernel_launch(void* const* d_in, const int* in_sizes, int n_in,
                              void* d_out, int out_size, void* d_ws, size_t ws_size,
                              hipStream_t stream) {
    const float* x     = (const float*)d_in[0];
    const float* temp  = (const float*)d_in[1];
    const float* w1    = (const float*)d_in[2];
    const float* b1    = (const float*)d_in[3];
    const float* w2    = (const float*)d_in[4];
    const float* b2    = (const float*)d_in[5];
    const float* w3    = (const float*)d_in[6];
    const float* b3    = (const float*)d_in[7];
    const float* wdwt  = (const float*)d_in[8];
    const float* bdwt  = (const float*)d_in[9];
    const float* widwt = (const float*)d_in[10];
    const float* bidwt = (const float*)d_in[11];
    const float* wproj = (const float*)d_in[12];
    float* out = (float*)d_out;

    char* W8 = (char*)d_ws;
    const size_t SLOT = 16777216;
    short* slotA = (short*)(W8);              // D0 -> I0
    short* slotB = (short*)(W8 + SLOT);       // D1
    short* slotC = (short*)(W8 + 2 * SLOT);   // Qb -> I2
    short* slotD = (short*)(W8 + 3 * SLOT);   // Kb
    char* P = W8 + 4 * SLOT;
    short* wF1    = (short*)P; P += 2 * 655360;
    short* wF2c   = (short*)P; P += 2 * 40960;
    short* wFk    = (short*)P; P += 2 * 65536;
    short* wpF    = (short*)P; P += 2 * 4096;
    short* wFq    = (short*)P; P += 2 * 4096;
    short* WfoldF = (short*)P; P += 2 * 131072;
    float* scr    = (float*)P;
    float* qss   = scr;
    float* kss   = scr + 128;
    float* gram  = scr + 256;
    float* bfold = scr + 4352;

    prep_all<<<3009, 256, 0, stream>>>(wdwt, widwt, w2, wproj, w1,
                                       wF1, wF2c, wFk, wpF, wFq, scr);

    // fused DWT + Q conv (x read once): D0 -> slotA, Qb -> slotC
    dwtq_kernel<<<dim3(2, 128, 2), 256, 0, stream>>>(x, wFq, b1, slotA, slotC);

    // DWT-branch 3x3 conv — v13 + setprio around MFMA cluster
    conv3_v13<<<dim3(64, 4, 2), 256, 0, stream>>>(slotA, wF1, bdwt, slotB);

    // K conv + gram (frees slotC after gram)
    kconv_mfma<<<dim3(4, 64, 2), 256, 0, stream>>>(slotB, wFk, b2, slotD);
    gram_mfma<<<dim3(128, 2), 256, 0, stream>>>(slotC, slotD, qss, kss, gram);

    // IDWT branch (slotA reused for I0, slotC reused for I2)
    idwt_kernel<<<8192, 256, 0, stream>>>(slotB, slotA);
    conv3_v14<<<dim3(128, 2, 2), 256, 0, stream>>>(slotA, wF2c, bidwt, slotC);

    // fold (softmax fused in — attn_kernel removed)
    fold_v3<<<dim3(16, 8), 256, 0, stream>>>(gram, qss, kss, temp, w3, b3, wproj,
                                             WfoldF, bfold);

    // fused (attn·V + proj) + idwt-branch proj
    final_mfma<<<dim3(256, 2), 256, 0, stream>>>(slotB, slotC, WfoldF, wpF, bfold, out);
}